// Round 11
// baseline (1080.220 us; speedup 1.0000x reference)
//
#include <hip/hip_runtime.h>

// ---------------------------------------------------------------------------
// LinearAttention (Linformer-style) on MI355X, bf16 MFMA pipeline, f32 accum.
// B=4 S=4096 D=1024 H=16 R=256 DK=64
// Round 11: q/k/v f32->bf16 converts FUSED into the QKV GEMM (gemm_qkv):
//           A staged f32->regs->cvt->swizzled ds_write (T14 write-late),
//           B via gload_lds; mixed vmcnt audited (5 ops/tile, VMW5).
//           Wo projection keeps bf16-A gemm_bt. attn/kpvp frozen (r10).
// ---------------------------------------------------------------------------

typedef __bf16 bf16;
typedef bf16 bf16x8 __attribute__((ext_vector_type(8)));
typedef bf16 bf16x4 __attribute__((ext_vector_type(4)));
typedef float f32x4 __attribute__((ext_vector_type(4)));

constexpr int BB = 4, SS = 4096, DD = 1024, HH = 16, RR = 256, DK = 64;

// q-projection output pre-scale: logits*log2e/8 so softmax uses exp2 directly
#define QSCALE 0.1803368801111204f

// async global->LDS, 16B per lane. ldsbase must be wave-uniform; HW writes
// lane l's 16B at ldsbase + l*16. gptr is per-lane.
__device__ __forceinline__ void gl2lds16(const void* g, void* l, int lane)
{
#if __has_builtin(__builtin_amdgcn_global_load_lds)
    auto gp = reinterpret_cast<const __attribute__((address_space(1))) void*>(
        reinterpret_cast<uintptr_t>(g));
    auto lp = reinterpret_cast<__attribute__((address_space(3))) void*>(
        reinterpret_cast<uintptr_t>(l));
    __builtin_amdgcn_global_load_lds(gp, lp, 16, 0, 0);
    (void)lane;
#else
    *(bf16x8*)((char*)l + lane * 16) = *(const bf16x8*)g;
#endif
}

#define VMW5  asm volatile("s_waitcnt vmcnt(5)" ::: "memory")
#define VMW3  asm volatile("s_waitcnt vmcnt(3)" ::: "memory")
#define VMW0  asm volatile("s_waitcnt vmcnt(0)" ::: "memory")
#define LGKM0 asm volatile("s_waitcnt lgkmcnt(0)" ::: "memory")

// ---------------------------------------------------------------------------
// Elementwise f32 -> bf16 convert, 8 elems/thread (weights + vp only now)
// ---------------------------------------------------------------------------
__global__ void cvt_f32_bf16(const float* __restrict__ in, bf16* __restrict__ out, int n)
{
    int i = (blockIdx.x * 256 + threadIdx.x) * 8;
    if (i < n) {
        float4 v0 = *(const float4*)(in + i);
        float4 v1 = *(const float4*)(in + i + 4);
        bf16x8 h;
        h[0] = (bf16)v0.x; h[1] = (bf16)v0.y; h[2] = (bf16)v0.z; h[3] = (bf16)v0.w;
        h[4] = (bf16)v1.x; h[5] = (bf16)v1.y; h[6] = (bf16)v1.z; h[7] = (bf16)v1.w;
        *(bf16x8*)(out + i) = h;
    }
}

// ---------------------------------------------------------------------------
// Tiled transpose + convert (used for kp f32 [DK,R] -> kpT bf16 [R,DK])
// ---------------------------------------------------------------------------
__global__ void transpose_cvt(const float* __restrict__ in, bf16* __restrict__ out,
                              int rows, int cols)
{
    __shared__ float t[64][65];
    const float* I = in + (size_t)blockIdx.z * rows * cols;
    bf16* O = out + (size_t)blockIdx.z * rows * cols;
    int c0 = blockIdx.x * 64, r0 = blockIdx.y * 64;
    int tx = threadIdx.x, ty = threadIdx.y;
#pragma unroll
    for (int i = ty; i < 64; i += 4)
        t[i][tx] = I[(size_t)(r0 + i) * cols + c0 + tx];
    __syncthreads();
#pragma unroll
    for (int i = ty; i < 64; i += 4)
        O[(size_t)(c0 + i) * rows + r0 + tx] = (bf16)t[tx][i];
}

// ---------------------------------------------------------------------------
// gemm_qkv: C[M,N](bf16) = (A_f32[M,K] * W_bf16[N,K]^T + bias) * oscale.
// K==1024. Round-8 geometry (256x128, BK=32, 8 waves, 48KB LDS, co-resident);
// A is staged f32 global -> regs -> cvt -> swizzled ds_write_b128 (write-late),
// B via gload_lds with pre-swizzled source. 5 vm ops/tile -> steady VMW5
// drains exactly tile t+1 (A-regs valid + B in LDS). Static regsE/regsO.
// LDS invariant (both operands): LDS[r][slot] = G[r][slot ^ ((r>>2)&3)].
// ---------------------------------------------------------------------------
__global__ __launch_bounds__(512, 4) void gemm_qkv(const float* __restrict__ A,
                                                   const bf16* __restrict__ W,
                                                   const float* __restrict__ bias,
                                                   bf16* __restrict__ Cp,
                                                   int M, int N, int K, float oscale)
{
    __shared__ bf16 As[2][256][32];
    __shared__ bf16 Bs[2][128][32];
    const int tid = threadIdx.x, wv = tid >> 6, lane = tid & 63;
    const int g = lane >> 4, lr = lane & 15;

    const int nwg = gridDim.x;
    const int cpx = nwg >> 3;                      // nwg % 8 == 0 (bijective)
    const int bid = blockIdx.x;
    const int swz = (bid & 7) * cpx + (bid >> 3);
    const int gx = N >> 7;
    const int mt = swz / gx, nt = swz % gx;
    const int m0 = mt * 256, n0 = nt * 128;
    const int wm = (wv >> 1) * 64, wn = (wv & 1) * 64;

    // B staging (gload_lds): row = wv*16 + lane>>2, source slot pre-swizzled
    const int srow = lane >> 2;
    const int scol = ((lane & 3) ^ ((lane >> 4) & 3)) * 8;

    // A reg-staging: thread -> row ar (2 threads/row), half ah (16 f32 = 64B)
    const int ar = tid >> 1, ah = tid & 1;
    const int axs = (ar >> 2) & 3;                 // row swizzle bits
    const float* Ag = A + (size_t)(m0 + ar) * 1024 + ah * 16;

    f32x4 acc[4][4] = {};
    float4 rE[4], rO[4];                           // static parity reg sets

    auto issueA = [&](float4* rr, int tk) {
#pragma unroll
        for (int ld = 0; ld < 4; ++ld)
            rr[ld] = *(const float4*)(Ag + tk * 32 + ld * 4);
    };
    auto writeA = [&](int buf, const float4* rr) {
        bf16x8 h0, h1;
        h0[0] = (bf16)rr[0].x; h0[1] = (bf16)rr[0].y; h0[2] = (bf16)rr[0].z; h0[3] = (bf16)rr[0].w;
        h0[4] = (bf16)rr[1].x; h0[5] = (bf16)rr[1].y; h0[6] = (bf16)rr[1].z; h0[7] = (bf16)rr[1].w;
        h1[0] = (bf16)rr[2].x; h1[1] = (bf16)rr[2].y; h1[2] = (bf16)rr[2].z; h1[3] = (bf16)rr[2].w;
        h1[4] = (bf16)rr[3].x; h1[5] = (bf16)rr[3].y; h1[6] = (bf16)rr[3].z; h1[7] = (bf16)rr[3].w;
        *(bf16x8*)&As[buf][ar][((ah * 2 + 0) ^ axs) * 8] = h0;
        *(bf16x8*)&As[buf][ar][((ah * 2 + 1) ^ axs) * 8] = h1;
    };
    auto stageB = [&](int buf, int tk) {
        gl2lds16(W + (size_t)(n0 + wv * 16 + srow) * 1024 + tk * 32 + scol,
                 &Bs[buf][wv * 16][0], lane);
    };

#define PHQ(PB, ISSUE_STMT, VM_STMT, WRITE_STMT)                                 \
    {                                                                            \
        const int so = (g ^ (lr >> 2)) << 4;                                     \
        bf16x8 aF[4], bF[4];                                                     \
        _Pragma("unroll") for (int mm = 0; mm < 4; ++mm)                         \
            aF[mm] = *(const bf16x8*)((const char*)&As[PB][wm + mm * 16 + lr][0] + so); \
        _Pragma("unroll") for (int nn = 0; nn < 4; ++nn)                         \
            bF[nn] = *(const bf16x8*)((const char*)&Bs[PB][wn + nn * 16 + lr][0] + so); \
        LGKM0;                                                                   \
        __builtin_amdgcn_s_barrier();              /* reads done, bufs free */   \
        ISSUE_STMT;                                /* tile t+2: 4 A-reg + 1 B */ \
        VM_STMT;                                   /* drain tile t+1 (5 ops) */  \
        WRITE_STMT;                                /* cvt+ds_write A(t+1) */     \
        LGKM0;                                     /* A-writes visible */        \
        __builtin_amdgcn_s_barrier();              /* t+1 buffer ready */        \
        __builtin_amdgcn_sched_barrier(0);                                       \
        __builtin_amdgcn_s_setprio(1);                                           \
        _Pragma("unroll") for (int mm = 0; mm < 4; ++mm) {                       \
            _Pragma("unroll") for (int nn = 0; nn < 4; ++nn) {                   \
                acc[mm][nn] = __builtin_amdgcn_mfma_f32_16x16x32_bf16(           \
                    aF[mm], bF[nn], acc[mm][nn], 0, 0, 0); } }                   \
        __builtin_amdgcn_s_setprio(0);                                           \
    }

    // prologue: issue tiles 0,1 (10 vm ops); VMW5 retires tile0; write A(0)
    issueA(rE, 0); stageB(0, 0);
    issueA(rO, 1); stageB(1, 1);
    VMW5;
    writeA(0, rE);
    LGKM0;
    __builtin_amdgcn_s_barrier();

#pragma unroll 1
    for (int tt = 0; tt < 15; ++tt) {
        const int t = tt * 2;
        PHQ(0, { issueA(rE, t + 2); stageB(0, t + 2); }, VMW5, writeA(1, rO));
        PHQ(1, { issueA(rO, t + 3); stageB(1, t + 3); }, VMW5, writeA(0, rE));
    }
    PHQ(0, (void)0, VMW0, writeA(1, rO));          // tile 30; retire+write 31
    PHQ(1, (void)0, (void)0, (void)0);             // tile 31
#undef PHQ

    float bv[4];
#pragma unroll
    for (int n = 0; n < 4; ++n) bv[n] = bias[n0 + wn + n * 16 + lr];

    // bounce through LDS (swizzled, 4KB/wave) -> 16B coalesced stores
    char* myb = (char*)&As[0][0][0] + wv * 4096;
#pragma unroll
    for (int mh = 0; mh < 2; ++mh) {
#pragma unroll
        for (int mm = 0; mm < 2; ++mm)
#pragma unroll
            for (int n = 0; n < 4; ++n) {
                int colb = (n * 16 + lr) * 2;
#pragma unroll
                for (int i = 0; i < 4; ++i) {
                    int row = mm * 16 + 4 * g + i;
                    *(bf16*)(myb + row * 128 + (colb ^ ((row & 7) << 4))) =
                        (bf16)((acc[mh * 2 + mm][n][i] + bv[n]) * oscale);
                }
            }
        __builtin_amdgcn_wave_barrier();
        bf16* Cb = Cp + (size_t)(m0 + wm + mh * 32) * N + n0 + wn;
#pragma unroll
        for (int it = 0; it < 4; ++it) {
            int r = it * 8 + (lane >> 3);
            int sl = lane & 7;
            bf16x8 vv = *(const bf16x8*)(myb + r * 128 + ((sl ^ (r & 7)) << 4));
            *(bf16x8*)(Cb + (size_t)r * N + sl * 8) = vv;
        }
        __builtin_amdgcn_wave_barrier();
    }
}

// ---------------------------------------------------------------------------
// gemm_bt (round-8 structure, frozen): bf16 A, f32 out — Wo projection only.
// ---------------------------------------------------------------------------
__global__ __launch_bounds__(512, 4) void gemm_bt(const bf16* __restrict__ A,
                                                  const bf16* __restrict__ W,
                                                  const float* __restrict__ bias,
                                                  float* __restrict__ Cp,
                                                  int M, int N, int K, float oscale)
{
    __shared__ bf16 As[2][256][32];
    __shared__ bf16 Bs[2][128][32];
    const int tid = threadIdx.x, wv = tid >> 6, lane = tid & 63;
    const int g = lane >> 4, lr = lane & 15;

    const int nwg = gridDim.x;
    const int cpx = nwg >> 3;
    const int bid = blockIdx.x;
    const int swz = (bid & 7) * cpx + (bid >> 3);
    const int gx = N >> 7;
    const int mt = swz / gx, nt = swz % gx;
    const int m0 = mt * 256, n0 = nt * 128;
    const int wm = (wv >> 1) * 64, wn = (wv & 1) * 64;

    const int srow = lane >> 2;
    const int scol = ((lane & 3) ^ ((lane >> 4) & 3)) * 8;

    f32x4 acc[4][4] = {};

    auto stageA = [&](int buf, int tk) {
#pragma unroll
        for (int s2 = 0; s2 < 2; ++s2) {
            int c = wv * 2 + s2;
            gl2lds16(A + (size_t)(m0 + c * 16 + srow) * 1024 + tk * 32 + scol,
                     &As[buf][c * 16][0], lane);
        }
    };
    auto stageB = [&](int buf, int tk) {
        gl2lds16(W + (size_t)(n0 + wv * 16 + srow) * 1024 + tk * 32 + scol,
                 &Bs[buf][wv * 16][0], lane);
    };

#define PHK(PB, STAGE_STMT, VM_STMT)                                             \
    {                                                                            \
        const int so = (g ^ (lr >> 2)) << 4;                                     \
        bf16x8 aF[4], bF[4];                                                     \
        _Pragma("unroll") for (int mm = 0; mm < 4; ++mm)                         \
            aF[mm] = *(const bf16x8*)((const char*)&As[PB][wm + mm * 16 + lr][0] + so); \
        _Pragma("unroll") for (int nn = 0; nn < 4; ++nn)                         \
            bF[nn] = *(const bf16x8*)((const char*)&Bs[PB][wn + nn * 16 + lr][0] + so); \
        LGKM0;                                                                   \
        __builtin_amdgcn_s_barrier();                                            \
        STAGE_STMT;                                                              \
        VM_STMT;                                                                 \
        __builtin_amdgcn_s_barrier();                                            \
        __builtin_amdgcn_sched_barrier(0);                                       \
        __builtin_amdgcn_s_setprio(1);                                           \
        _Pragma("unroll") for (int mm = 0; mm < 4; ++mm) {                       \
            _Pragma("unroll") for (int nn = 0; nn < 4; ++nn) {                   \
                acc[mm][nn] = __builtin_amdgcn_mfma_f32_16x16x32_bf16(           \
                    aF[mm], bF[nn], acc[mm][nn], 0, 0, 0); } }                   \
        __builtin_amdgcn_s_setprio(0);                                           \
    }

    stageA(0, 0); stageB(0, 0);
    stageA(1, 1); stageB(1, 1);
    VMW3;
    __builtin_amdgcn_s_barrier();

#pragma unroll 1
    for (int t = 0; t < 30; ++t) {
        const int pb = t & 1;
        PHK(pb, { stageA(pb, t + 2); stageB(pb, t + 2); }, VMW3);
    }
    PHK(0, (void)0, VMW0);
    PHK(1, (void)0, (void)0);
#undef PHK

    float bv[4];
#pragma unroll
    for (int n = 0; n < 4; ++n) bv[n] = bias[n0 + wn + n * 16 + lr];

#pragma unroll
    for (int n = 0; n < 4; ++n) {
        int col = n0 + wn + n * 16 + lr;
#pragma unroll
        for (int m = 0; m < 4; ++m) {
            int row = m0 + wm + m * 16 + 4 * g;
#pragma unroll
            for (int i = 0; i < 4; ++i)
                Cp[(size_t)(row + i) * N + col] = (acc[m][n][i] + bv[n]) * oscale;
        }
    }
}

// ---------------------------------------------------------------------------
// kp[b,h,d,r] += sum_{s in chunk} X[b,s,h*64+d] * E[h,s,r]
// E read DIRECTLY as f32 [H,S,R] (fused transpose+convert in registers).
// ---------------------------------------------------------------------------
__global__ __launch_bounds__(256) void kpvp_gemm(const bf16* __restrict__ X,
                                                 const float* __restrict__ E,
                                                 float* __restrict__ out)
{
    __shared__ bf16 Ak[64][40];
    const int b = blockIdx.z, h = blockIdx.y;
    const int s0 = blockIdx.x * 512;
    const int tid = threadIdx.x, wv = tid >> 6, lane = tid & 63;
    const int g = lane >> 4, lr = lane & 15;
    const float* Eh = E + (size_t)h * SS * RR;
    const int rbase = wv * 64 + lr;
    f32x4 acc[4][4] = {};

    for (int kt = 0; kt < 512; kt += 32) {
        const int sb = s0 + kt;
        __syncthreads();
        float ef[4][8];
        const float* Eb = Eh + (size_t)(sb + g * 8) * RR + rbase;
#pragma unroll
        for (int n = 0; n < 4; ++n)
#pragma unroll
            for (int j = 0; j < 8; ++j)
                ef[n][j] = Eb[(size_t)j * RR + n * 16];
        {
            int sl = tid >> 3, dblk = (tid & 7) * 8;
            bf16x8 v = *(const bf16x8*)(X + ((size_t)b * SS + sb + sl) * DD + h * DK + dblk);
#pragma unroll
            for (int j = 0; j < 8; ++j) Ak[dblk + j][sl] = v[j];
        }
        bf16x8 bb[4];
#pragma unroll
        for (int n = 0; n < 4; ++n)
#pragma unroll
            for (int j = 0; j < 8; ++j)
                bb[n][j] = (bf16)ef[n][j];
        __syncthreads();

        bf16x8 a[4];
#pragma unroll
        for (int m = 0; m < 4; ++m) a[m] = *(const bf16x8*)&Ak[m * 16 + lr][g * 8];
#pragma unroll
        for (int m = 0; m < 4; ++m)
#pragma unroll
            for (int n = 0; n < 4; ++n)
                acc[m][n] = __builtin_amdgcn_mfma_f32_16x16x32_bf16(a[m], bb[n], acc[m][n], 0, 0, 0);
    }

    float* o = out + ((size_t)(b * HH + h)) * DK * RR;
#pragma unroll
    for (int m = 0; m < 4; ++m)
#pragma unroll
        for (int n = 0; n < 4; ++n) {
            int r = wv * 64 + n * 16 + lr;
#pragma unroll
            for (int i = 0; i < 4; ++i)
                atomicAdd(o + (size_t)(m * 16 + 4 * g + i) * RR + r, acc[m][n][i]);
        }
}

// ---------------------------------------------------------------------------
// Fused attention (round-8 structure, frozen at 57us).
// ---------------------------------------------------------------------------
__global__ __launch_bounds__(512) void attn_fused(const bf16* __restrict__ qb,
                                                  const bf16* __restrict__ kpt,
                                                  const bf16* __restrict__ vpb,
                                                  bf16* __restrict__ ctx)
{
    __shared__ bf16 KPs[256][72];
    __shared__ bf16 VPs[64][264];
    __shared__ bf16 Ps[8][16][264];
    const int b = blockIdx.z, h = blockIdx.y, qt = blockIdx.x;
    const int tid = threadIdx.x, wv = tid >> 6, lane = tid & 63;
    const int g = lane >> 4, lr = lane & 15;
    const bf16* kph = kpt + ((size_t)(b * HH + h)) * RR * DK;
    const bf16* vph = vpb + ((size_t)(b * HH + h)) * DK * RR;

#pragma unroll
    for (int p = 0; p < 4; ++p) {
        int f = p * 512 + tid;
        *(bf16x8*)&KPs[f >> 3][(f & 7) * 8] = *(const bf16x8*)(kph + (size_t)f * 8);
        *(bf16x8*)&VPs[f >> 5][(f & 31) * 8] = *(const bf16x8*)(vph + (size_t)f * 8);
    }

    const bf16* qbase = qb + (size_t)b * SS * DD + h * DK;
    int row0 = qt * 1024 + wv * 16;
    bf16x8 aq0 = *(const bf16x8*)(qbase + (size_t)(row0 + lr) * DD + g * 8);
    bf16x8 aq1 = *(const bf16x8*)(qbase + (size_t)(row0 + lr) * DD + 32 + g * 8);
    __syncthreads();

    for (int it = 0; it < 8; ++it) {
        f32x4 acc[16] = {};
        __builtin_amdgcn_s_setprio(1);
#pragma unroll
        for (int nf = 0; nf < 16; ++nf) {
            bf16x8 b0 = *(const bf16x8*)&KPs[nf * 16 + lr][g * 8];
            bf16x8 b1 = *(const bf16x8*)&KPs[nf * 16 + lr][32 + g * 8];
            acc[nf] = __builtin_amdgcn_mfma_f32_16x16x32_bf16(aq0, b0, acc[nf], 0, 0, 0);
            acc[nf] = __builtin_amdgcn_mfma_f32_16x16x32_bf16(aq1, b1, acc[nf], 0, 0, 0);
        }
        __builtin_amdgcn_s_setprio(0);

        bf16x8 aqn0 = aq0, aqn1 = aq1;
        if (it < 7) {
            const bf16* qr = qbase + (size_t)(row0 + 128 + lr) * DD;
            aqn0 = *(const bf16x8*)(qr + g * 8);
            aqn1 = *(const bf16x8*)(qr + 32 + g * 8);
        }

        float rs[4];
#pragma unroll
        for (int i = 0; i < 4; ++i) {
            float s = 0.f;
#pragma unroll
            for (int nf = 0; nf < 16; ++nf) {
                float pv = exp2f(acc[nf][i]);
                acc[nf][i] = pv;
                s += pv;
            }
#pragma unroll
            for (int msk = 1; msk < 16; msk <<= 1) s += __shfl_xor(s, msk, 64);
            rs[i] = 1.f / s;
        }

#pragma unroll
        for (int nf = 0; nf < 16; ++nf)
#pragma unroll
            for (int i = 0; i < 4; ++i)
                Ps[wv][4 * g + i][nf * 16 + lr] = (bf16)acc[nf][i];
        __builtin_amdgcn_wave_barrier();

        f32x4 o[4] = {};
        __builtin_amdgcn_s_setprio(1);
#pragma unroll
        for (int ks = 0; ks < 8; ++ks) {
            bf16x8 pa = *(const bf16x8*)&Ps[wv][lr][ks * 32 + g * 8];
#pragma unroll
            for (int n = 0; n < 4; ++n) {
                bf16x8 vb = *(const bf16x8*)&VPs[n * 16 + lr][ks * 32 + g * 8];
                o[n] = __builtin_amdgcn_mfma_f32_16x16x32_bf16(pa, vb, o[n], 0, 0, 0);
            }
        }
        __builtin_amdgcn_s_setprio(0);
        __builtin_amdgcn_wave_barrier();

#pragma unroll
        for (int n = 0; n < 4; ++n)
#pragma unroll
            for (int i = 0; i < 4; ++i)
                Ps[wv][4 * g + i][n * 16 + lr] = (bf16)(o[n][i] * rs[i]);
        __builtin_amdgcn_wave_barrier();
        bf16* crow = ctx + (size_t)(b * SS + row0) * DD + h * DK;
#pragma unroll
        for (int p = 0; p < 2; ++p) {
            int r = p * 8 + (lane >> 3), c = (lane & 7) * 8;
            bf16x8 ov = *(const bf16x8*)&Ps[wv][r][c];
            *(bf16x8*)(crow + (size_t)r * DD + c) = ov;
        }
        __builtin_amdgcn_wave_barrier();

        aq0 = aqn0; aq1 = aqn1;
        row0 += 128;
    }
}

// ---------------------------------------------------------------------------
extern "C" void kernel_launch(void* const* d_in, const int* in_sizes, int n_in,
                              void* d_out, int out_size, void* d_ws, size_t ws_size,
                              hipStream_t stream)
{
    const float* query = (const float*)d_in[0];
    const float* key   = (const float*)d_in[1];
    const float* value = (const float*)d_in[2];
    const float* Wq = (const float*)d_in[3];  const float* bq = (const float*)d_in[4];
    const float* Wk = (const float*)d_in[5];  const float* bk = (const float*)d_in[6];
    const float* Wv = (const float*)d_in[7];  const float* bv = (const float*)d_in[8];
    const float* Wo = (const float*)d_in[9];  const float* bo = (const float*)d_in[10];
    const float* E  = (const float*)d_in[11];
    const float* F  = (const float*)d_in[12];

    char* w = (char*)d_ws;
    size_t off = 0;
    auto alloc = [&](size_t bytes) -> char* {
        char* p = w + off;
        off += (bytes + 255) & ~(size_t)255;
        return p;
    };

    const size_t DW   = (size_t)DD * DD;           // 1M
    const size_t BSD  = (size_t)BB * SS * DD;      // 16.78M
    const size_t BHDR = (size_t)BB * HH * DK * RR; // 4.19M

    bf16* wqb = (bf16*)alloc(DW * 2);
    bf16* wkb = (bf16*)alloc(DW * 2);
    bf16* wvb = (bf16*)alloc(DW * 2);
    bf16* wob = (bf16*)alloc(DW * 2);
    bf16* scr1 = (bf16*)alloc(BSD * 2);            // scratch: kpf/vpf
    bf16* scr2 = (bf16*)alloc(BSD * 2);            // scratch: kpt/vpbb
    bf16* scr3 = (bf16*)alloc(BSD * 2);            // scratch: ctx
    bf16* qbuf = (bf16*)alloc(BSD * 2);
    bf16* kbuf = (bf16*)alloc(BSD * 2);
    bf16* vbuf = (bf16*)alloc(BSD * 2);
    if (off > ws_size) return;

    float* kpf  = (float*)scr1;                    // BHDR f32
    float* vpf  = kpf + BHDR;                      // BHDR f32
    bf16*  kpt  = (bf16*)scr2;                     // BHDR bf16 [B,H,R,DK]
    bf16*  vpbb = kpt + BHDR;                      // BHDR bf16 [B,H,DK,R]
    bf16*  ctx  = (bf16*)scr3;                     // BSD bf16

    // 1. weight converts only (activation converts fused into gemm_qkv)
    cvt_f32_bf16<<<(int)(DW / 2048), 256, 0, stream>>>(Wq, wqb, (int)DW);
    cvt_f32_bf16<<<(int)(DW / 2048), 256, 0, stream>>>(Wk, wkb, (int)DW);
    cvt_f32_bf16<<<(int)(DW / 2048), 256, 0, stream>>>(Wv, wvb, (int)DW);
    cvt_f32_bf16<<<(int)(DW / 2048), 256, 0, stream>>>(Wo, wob, (int)DW);

    // 2. QKV projections: f32 inputs read directly, cvt fused in staging
    const int nwg = ((BB * SS) / 256) * (DD / 128);   // 512, % 8 == 0
    gemm_qkv<<<nwg, 512, 0, stream>>>(query, wqb, bq, qbuf, BB * SS, DD, DD, QSCALE);
    gemm_qkv<<<nwg, 512, 0, stream>>>(key,   wkb, bk, kbuf, BB * SS, DD, DD, 1.0f);
    gemm_qkv<<<nwg, 512, 0, stream>>>(value, wvb, bv, vbuf, BB * SS, DD, DD, 1.0f);

    // 3. kp/vp = k^T E, v^T F — E/F read directly as f32 (fused transpose+cvt)
    hipMemsetAsync(kpf, 0, BHDR * 4 * 2, stream);
    kpvp_gemm<<<dim3(SS / 512, HH, BB), 256, 0, stream>>>(kbuf, E, kpf);
    kpvp_gemm<<<dim3(SS / 512, HH, BB), 256, 0, stream>>>(vbuf, F, vpf);

    // 4. kp -> kpT bf16 [B,H,R,DK]; vp -> bf16 [B,H,DK,R]
    dim3 tb(64, 4);
    transpose_cvt<<<dim3(RR / 64, DK / 64, BB * HH), tb, 0, stream>>>(kpf, kpt, DK, RR);
    cvt_f32_bf16<<<(int)(BHDR / 2048), 256, 0, stream>>>(vpf, vpbb, (int)BHDR);

    // 5. fused softmax attention
    attn_fused<<<dim3(SS / 1024, HH, BB), 512, 0, stream>>>(qbuf, kpt, vpbb, ctx);

    // 6. output projection -> f32 d_out
    gemm_bt<<<nwg, 512, 0, stream>>>(ctx, wob, bo, (float*)d_out, BB * SS, DD, DD, 1.0f);
}

// Round 12
// 900.583 us; speedup vs baseline: 1.1995x; 1.1995x over previous
//
#include <hip/hip_runtime.h>

// ---------------------------------------------------------------------------
// LinearAttention (Linformer-style) on MI355X, bf16 MFMA pipeline, f32 accum.
// B=4 S=4096 D=1024 H=16 R=256 DK=64
// Round 12: gemm_qkv spill fix — r11 passed reg-arrays by pointer into
//           lambdas (rule #20 violation: address taken -> scratch; VGPR=64,
//           745MB scratch writes). Now named float4 scalars + statement
//           macros, zero address-taking. Schedule unchanged (VMW5 mixed).
// ---------------------------------------------------------------------------

typedef __bf16 bf16;
typedef bf16 bf16x8 __attribute__((ext_vector_type(8)));
typedef bf16 bf16x4 __attribute__((ext_vector_type(4)));
typedef float f32x4 __attribute__((ext_vector_type(4)));

constexpr int BB = 4, SS = 4096, DD = 1024, HH = 16, RR = 256, DK = 64;

// q-projection output pre-scale: logits*log2e/8 so softmax uses exp2 directly
#define QSCALE 0.1803368801111204f

// async global->LDS, 16B per lane. ldsbase must be wave-uniform; HW writes
// lane l's 16B at ldsbase + l*16. gptr is per-lane.
__device__ __forceinline__ void gl2lds16(const void* g, void* l, int lane)
{
#if __has_builtin(__builtin_amdgcn_global_load_lds)
    auto gp = reinterpret_cast<const __attribute__((address_space(1))) void*>(
        reinterpret_cast<uintptr_t>(g));
    auto lp = reinterpret_cast<__attribute__((address_space(3))) void*>(
        reinterpret_cast<uintptr_t>(l));
    __builtin_amdgcn_global_load_lds(gp, lp, 16, 0, 0);
    (void)lane;
#else
    *(bf16x8*)((char*)l + lane * 16) = *(const bf16x8*)g;
#endif
}

#define VMW5  asm volatile("s_waitcnt vmcnt(5)" ::: "memory")
#define VMW3  asm volatile("s_waitcnt vmcnt(3)" ::: "memory")
#define VMW0  asm volatile("s_waitcnt vmcnt(0)" ::: "memory")
#define LGKM0 asm volatile("s_waitcnt lgkmcnt(0)" ::: "memory")

// ---------------------------------------------------------------------------
// Elementwise f32 -> bf16 convert, 8 elems/thread (weights + vp only)
// ---------------------------------------------------------------------------
__global__ void cvt_f32_bf16(const float* __restrict__ in, bf16* __restrict__ out, int n)
{
    int i = (blockIdx.x * 256 + threadIdx.x) * 8;
    if (i < n) {
        float4 v0 = *(const float4*)(in + i);
        float4 v1 = *(const float4*)(in + i + 4);
        bf16x8 h;
        h[0] = (bf16)v0.x; h[1] = (bf16)v0.y; h[2] = (bf16)v0.z; h[3] = (bf16)v0.w;
        h[4] = (bf16)v1.x; h[5] = (bf16)v1.y; h[6] = (bf16)v1.z; h[7] = (bf16)v1.w;
        *(bf16x8*)(out + i) = h;
    }
}

// ---------------------------------------------------------------------------
// Tiled transpose + convert (used for kp f32 [DK,R] -> kpT bf16 [R,DK])
// ---------------------------------------------------------------------------
__global__ void transpose_cvt(const float* __restrict__ in, bf16* __restrict__ out,
                              int rows, int cols)
{
    __shared__ float t[64][65];
    const float* I = in + (size_t)blockIdx.z * rows * cols;
    bf16* O = out + (size_t)blockIdx.z * rows * cols;
    int c0 = blockIdx.x * 64, r0 = blockIdx.y * 64;
    int tx = threadIdx.x, ty = threadIdx.y;
#pragma unroll
    for (int i = ty; i < 64; i += 4)
        t[i][tx] = I[(size_t)(r0 + i) * cols + c0 + tx];
    __syncthreads();
#pragma unroll
    for (int i = ty; i < 64; i += 4)
        O[(size_t)(c0 + i) * rows + r0 + tx] = (bf16)t[tx][i];
}

// ---------------------------------------------------------------------------
// gemm_qkv: C[M,N](bf16) = (A_f32[M,K] * W_bf16[N,K]^T + bias) * oscale.
// K==1024. Round-8 geometry (256x128, BK=32, 8 waves, 48KB LDS);
// A staged f32 global -> NAMED float4 regs -> cvt -> swizzled ds_write_b128
// (write-late); B via gload_lds pre-swizzled. 5 vm ops/tile, steady VMW5
// drains exactly tile t+1. All staging regs are named scalars (no arrays,
// no address-taking) so nothing demotes to scratch.
// LDS invariant (both operands): LDS[r][slot8] = G[r][slot8 ^ ((r>>2)&3)].
// ---------------------------------------------------------------------------
__global__ __launch_bounds__(512, 4) void gemm_qkv(const float* __restrict__ A,
                                                   const bf16* __restrict__ W,
                                                   const float* __restrict__ bias,
                                                   bf16* __restrict__ Cp,
                                                   int M, int N, int K, float oscale)
{
    __shared__ bf16 As[2][256][32];
    __shared__ bf16 Bs[2][128][32];
    const int tid = threadIdx.x, wv = tid >> 6, lane = tid & 63;
    const int g = lane >> 4, lr = lane & 15;

    const int nwg = gridDim.x;
    const int cpx = nwg >> 3;                      // nwg % 8 == 0 (bijective)
    const int bid = blockIdx.x;
    const int swz = (bid & 7) * cpx + (bid >> 3);
    const int gx = N >> 7;
    const int mt = swz / gx, nt = swz % gx;
    const int m0 = mt * 256, n0 = nt * 128;
    const int wm = (wv >> 1) * 64, wn = (wv & 1) * 64;

    // B staging (gload_lds): row = wv*16 + lane>>2, source slot pre-swizzled
    const int srow = lane >> 2;
    const int scol = ((lane & 3) ^ ((lane >> 4) & 3)) * 8;

    // A reg-staging: thread -> row ar (2 threads/row), half ah (16 f32 = 64B)
    const int ar = tid >> 1, ah = tid & 1;
    const int axs = (ar >> 2) & 3;                 // row swizzle bits
    const float* Ag = A + (size_t)(m0 + ar) * 1024 + ah * 16;

    f32x4 acc[4][4] = {};
    float4 rE0, rE1, rE2, rE3, rO0, rO1, rO2, rO3; // named parity sets

#define ISSUEA(a0, a1, a2, a3, tk)                                               \
    {                                                                            \
        const float* ap_ = Ag + (size_t)(tk) * 32;                               \
        a0 = *(const float4*)(ap_);                                              \
        a1 = *(const float4*)(ap_ + 4);                                          \
        a2 = *(const float4*)(ap_ + 8);                                          \
        a3 = *(const float4*)(ap_ + 12);                                         \
    }
#define WRITEA(buf, a0, a1, a2, a3)                                              \
    {                                                                            \
        bf16x8 h0_, h1_;                                                         \
        h0_[0] = (bf16)a0.x; h0_[1] = (bf16)a0.y; h0_[2] = (bf16)a0.z; h0_[3] = (bf16)a0.w; \
        h0_[4] = (bf16)a1.x; h0_[5] = (bf16)a1.y; h0_[6] = (bf16)a1.z; h0_[7] = (bf16)a1.w; \
        h1_[0] = (bf16)a2.x; h1_[1] = (bf16)a2.y; h1_[2] = (bf16)a2.z; h1_[3] = (bf16)a2.w; \
        h1_[4] = (bf16)a3.x; h1_[5] = (bf16)a3.y; h1_[6] = (bf16)a3.z; h1_[7] = (bf16)a3.w; \
        *(bf16x8*)&As[buf][ar][((ah * 2 + 0) ^ axs) * 8] = h0_;                  \
        *(bf16x8*)&As[buf][ar][((ah * 2 + 1) ^ axs) * 8] = h1_;                  \
    }

    auto stageB = [&](int buf, int tk) {
        gl2lds16(W + (size_t)(n0 + wv * 16 + srow) * 1024 + tk * 32 + scol,
                 &Bs[buf][wv * 16][0], lane);
    };

#define PHQ(PB, ISSUE_STMT, VM_STMT, WRITE_STMT)                                 \
    {                                                                            \
        const int so = (g ^ (lr >> 2)) << 4;                                     \
        bf16x8 aF[4], bF[4];                                                     \
        _Pragma("unroll") for (int mm = 0; mm < 4; ++mm)                         \
            aF[mm] = *(const bf16x8*)((const char*)&As[PB][wm + mm * 16 + lr][0] + so); \
        _Pragma("unroll") for (int nn = 0; nn < 4; ++nn)                         \
            bF[nn] = *(const bf16x8*)((const char*)&Bs[PB][wn + nn * 16 + lr][0] + so); \
        LGKM0;                                                                   \
        __builtin_amdgcn_s_barrier();              /* reads done, bufs free */   \
        ISSUE_STMT;                                /* tile t+2: 4 A-reg + 1 B */ \
        VM_STMT;                                   /* drain tile t+1 (5 ops) */  \
        WRITE_STMT;                                /* cvt+ds_write A(t+1) */     \
        LGKM0;                                     /* A-writes visible */        \
        __builtin_amdgcn_s_barrier();              /* t+1 buffer ready */        \
        __builtin_amdgcn_sched_barrier(0);                                       \
        __builtin_amdgcn_s_setprio(1);                                           \
        _Pragma("unroll") for (int mm = 0; mm < 4; ++mm) {                       \
            _Pragma("unroll") for (int nn = 0; nn < 4; ++nn) {                   \
                acc[mm][nn] = __builtin_amdgcn_mfma_f32_16x16x32_bf16(           \
                    aF[mm], bF[nn], acc[mm][nn], 0, 0, 0); } }                   \
        __builtin_amdgcn_s_setprio(0);                                           \
    }

    // prologue: issue tiles 0,1 (10 vm ops); VMW5 retires tile0; write A(0)
    ISSUEA(rE0, rE1, rE2, rE3, 0); stageB(0, 0);
    ISSUEA(rO0, rO1, rO2, rO3, 1); stageB(1, 1);
    VMW5;
    WRITEA(0, rE0, rE1, rE2, rE3);
    LGKM0;
    __builtin_amdgcn_s_barrier();

#pragma unroll 1
    for (int tt = 0; tt < 15; ++tt) {
        const int t = tt * 2;
        PHQ(0, { ISSUEA(rE0, rE1, rE2, rE3, t + 2); stageB(0, t + 2); },
            VMW5, WRITEA(1, rO0, rO1, rO2, rO3));
        PHQ(1, { ISSUEA(rO0, rO1, rO2, rO3, t + 3); stageB(1, t + 3); },
            VMW5, WRITEA(0, rE0, rE1, rE2, rE3));
    }
    PHQ(0, (void)0, VMW0, WRITEA(1, rO0, rO1, rO2, rO3));  // tile 30
    PHQ(1, (void)0, (void)0, (void)0);                      // tile 31
#undef PHQ
#undef ISSUEA
#undef WRITEA

    float bv[4];
#pragma unroll
    for (int n = 0; n < 4; ++n) bv[n] = bias[n0 + wn + n * 16 + lr];

    // bounce through LDS (swizzled, 4KB/wave) -> 16B coalesced stores
    char* myb = (char*)&As[0][0][0] + wv * 4096;
#pragma unroll
    for (int mh = 0; mh < 2; ++mh) {
#pragma unroll
        for (int mm = 0; mm < 2; ++mm)
#pragma unroll
            for (int n = 0; n < 4; ++n) {
                int colb = (n * 16 + lr) * 2;
#pragma unroll
                for (int i = 0; i < 4; ++i) {
                    int row = mm * 16 + 4 * g + i;
                    *(bf16*)(myb + row * 128 + (colb ^ ((row & 7) << 4))) =
                        (bf16)((acc[mh * 2 + mm][n][i] + bv[n]) * oscale);
                }
            }
        __builtin_amdgcn_wave_barrier();
        bf16* Cb = Cp + (size_t)(m0 + wm + mh * 32) * N + n0 + wn;
#pragma unroll
        for (int it = 0; it < 4; ++it) {
            int r = it * 8 + (lane >> 3);
            int sl = lane & 7;
            bf16x8 vv = *(const bf16x8*)(myb + r * 128 + ((sl ^ (r & 7)) << 4));
            *(bf16x8*)(Cb + (size_t)r * N + sl * 8) = vv;
        }
        __builtin_amdgcn_wave_barrier();
    }
}

// ---------------------------------------------------------------------------
// gemm_bt (round-8 structure, frozen): bf16 A, f32 out — Wo projection only.
// ---------------------------------------------------------------------------
__global__ __launch_bounds__(512, 4) void gemm_bt(const bf16* __restrict__ A,
                                                  const bf16* __restrict__ W,
                                                  const float* __restrict__ bias,
                                                  float* __restrict__ Cp,
                                                  int M, int N, int K, float oscale)
{
    __shared__ bf16 As[2][256][32];
    __shared__ bf16 Bs[2][128][32];
    const int tid = threadIdx.x, wv = tid >> 6, lane = tid & 63;
    const int g = lane >> 4, lr = lane & 15;

    const int nwg = gridDim.x;
    const int cpx = nwg >> 3;
    const int bid = blockIdx.x;
    const int swz = (bid & 7) * cpx + (bid >> 3);
    const int gx = N >> 7;
    const int mt = swz / gx, nt = swz % gx;
    const int m0 = mt * 256, n0 = nt * 128;
    const int wm = (wv >> 1) * 64, wn = (wv & 1) * 64;

    const int srow = lane >> 2;
    const int scol = ((lane & 3) ^ ((lane >> 4) & 3)) * 8;

    f32x4 acc[4][4] = {};

    auto stageA = [&](int buf, int tk) {
#pragma unroll
        for (int s2 = 0; s2 < 2; ++s2) {
            int c = wv * 2 + s2;
            gl2lds16(A + (size_t)(m0 + c * 16 + srow) * 1024 + tk * 32 + scol,
                     &As[buf][c * 16][0], lane);
        }
    };
    auto stageB = [&](int buf, int tk) {
        gl2lds16(W + (size_t)(n0 + wv * 16 + srow) * 1024 + tk * 32 + scol,
                 &Bs[buf][wv * 16][0], lane);
    };

#define PHK(PB, STAGE_STMT, VM_STMT)                                             \
    {                                                                            \
        const int so = (g ^ (lr >> 2)) << 4;                                     \
        bf16x8 aF[4], bF[4];                                                     \
        _Pragma("unroll") for (int mm = 0; mm < 4; ++mm)                         \
            aF[mm] = *(const bf16x8*)((const char*)&As[PB][wm + mm * 16 + lr][0] + so); \
        _Pragma("unroll") for (int nn = 0; nn < 4; ++nn)                         \
            bF[nn] = *(const bf16x8*)((const char*)&Bs[PB][wn + nn * 16 + lr][0] + so); \
        LGKM0;                                                                   \
        __builtin_amdgcn_s_barrier();                                            \
        STAGE_STMT;                                                              \
        VM_STMT;                                                                 \
        __builtin_amdgcn_s_barrier();                                            \
        __builtin_amdgcn_sched_barrier(0);                                       \
        __builtin_amdgcn_s_setprio(1);                                           \
        _Pragma("unroll") for (int mm = 0; mm < 4; ++mm) {                       \
            _Pragma("unroll") for (int nn = 0; nn < 4; ++nn) {                   \
                acc[mm][nn] = __builtin_amdgcn_mfma_f32_16x16x32_bf16(           \
                    aF[mm], bF[nn], acc[mm][nn], 0, 0, 0); } }                   \
        __builtin_amdgcn_s_setprio(0);                                           \
    }

    stageA(0, 0); stageB(0, 0);
    stageA(1, 1); stageB(1, 1);
    VMW3;
    __builtin_amdgcn_s_barrier();

#pragma unroll 1
    for (int t = 0; t < 30; ++t) {
        const int pb = t & 1;
        PHK(pb, { stageA(pb, t + 2); stageB(pb, t + 2); }, VMW3);
    }
    PHK(0, (void)0, VMW0);
    PHK(1, (void)0, (void)0);
#undef PHK

    float bv[4];
#pragma unroll
    for (int n = 0; n < 4; ++n) bv[n] = bias[n0 + wn + n * 16 + lr];

#pragma unroll
    for (int n = 0; n < 4; ++n) {
        int col = n0 + wn + n * 16 + lr;
#pragma unroll
        for (int m = 0; m < 4; ++m) {
            int row = m0 + wm + m * 16 + 4 * g;
#pragma unroll
            for (int i = 0; i < 4; ++i)
                Cp[(size_t)(row + i) * N + col] = (acc[m][n][i] + bv[n]) * oscale;
        }
    }
}

// ---------------------------------------------------------------------------
// kp[b,h,d,r] += sum_{s in chunk} X[b,s,h*64+d] * E[h,s,r]
// E read DIRECTLY as f32 [H,S,R] (fused transpose+convert in registers).
// ---------------------------------------------------------------------------
__global__ __launch_bounds__(256) void kpvp_gemm(const bf16* __restrict__ X,
                                                 const float* __restrict__ E,
                                                 float* __restrict__ out)
{
    __shared__ bf16 Ak[64][40];
    const int b = blockIdx.z, h = blockIdx.y;
    const int s0 = blockIdx.x * 512;
    const int tid = threadIdx.x, wv = tid >> 6, lane = tid & 63;
    const int g = lane >> 4, lr = lane & 15;
    const float* Eh = E + (size_t)h * SS * RR;
    const int rbase = wv * 64 + lr;
    f32x4 acc[4][4] = {};

    for (int kt = 0; kt < 512; kt += 32) {
        const int sb = s0 + kt;
        __syncthreads();
        float ef[4][8];
        const float* Eb = Eh + (size_t)(sb + g * 8) * RR + rbase;
#pragma unroll
        for (int n = 0; n < 4; ++n)
#pragma unroll
            for (int j = 0; j < 8; ++j)
                ef[n][j] = Eb[(size_t)j * RR + n * 16];
        {
            int sl = tid >> 3, dblk = (tid & 7) * 8;
            bf16x8 v = *(const bf16x8*)(X + ((size_t)b * SS + sb + sl) * DD + h * DK + dblk);
#pragma unroll
            for (int j = 0; j < 8; ++j) Ak[dblk + j][sl] = v[j];
        }
        bf16x8 bb[4];
#pragma unroll
        for (int n = 0; n < 4; ++n)
#pragma unroll
            for (int j = 0; j < 8; ++j)
                bb[n][j] = (bf16)ef[n][j];
        __syncthreads();

        bf16x8 a[4];
#pragma unroll
        for (int m = 0; m < 4; ++m) a[m] = *(const bf16x8*)&Ak[m * 16 + lr][g * 8];
#pragma unroll
        for (int m = 0; m < 4; ++m)
#pragma unroll
            for (int n = 0; n < 4; ++n)
                acc[m][n] = __builtin_amdgcn_mfma_f32_16x16x32_bf16(a[m], bb[n], acc[m][n], 0, 0, 0);
    }

    float* o = out + ((size_t)(b * HH + h)) * DK * RR;
#pragma unroll
    for (int m = 0; m < 4; ++m)
#pragma unroll
        for (int n = 0; n < 4; ++n) {
            int r = wv * 64 + n * 16 + lr;
#pragma unroll
            for (int i = 0; i < 4; ++i)
                atomicAdd(o + (size_t)(m * 16 + 4 * g + i) * RR + r, acc[m][n][i]);
        }
}

// ---------------------------------------------------------------------------
// Fused attention (round-8 structure, frozen at 57us).
// ---------------------------------------------------------------------------
__global__ __launch_bounds__(512) void attn_fused(const bf16* __restrict__ qb,
                                                  const bf16* __restrict__ kpt,
                                                  const bf16* __restrict__ vpb,
                                                  bf16* __restrict__ ctx)
{
    __shared__ bf16 KPs[256][72];
    __shared__ bf16 VPs[64][264];
    __shared__ bf16 Ps[8][16][264];
    const int b = blockIdx.z, h = blockIdx.y, qt = blockIdx.x;
    const int tid = threadIdx.x, wv = tid >> 6, lane = tid & 63;
    const int g = lane >> 4, lr = lane & 15;
    const bf16* kph = kpt + ((size_t)(b * HH + h)) * RR * DK;
    const bf16* vph = vpb + ((size_t)(b * HH + h)) * DK * RR;

#pragma unroll
    for (int p = 0; p < 4; ++p) {
        int f = p * 512 + tid;
        *(bf16x8*)&KPs[f >> 3][(f & 7) * 8] = *(const bf16x8*)(kph + (size_t)f * 8);
        *(bf16x8*)&VPs[f >> 5][(f & 31) * 8] = *(const bf16x8*)(vph + (size_t)f * 8);
    }

    const bf16* qbase = qb + (size_t)b * SS * DD + h * DK;
    int row0 = qt * 1024 + wv * 16;
    bf16x8 aq0 = *(const bf16x8*)(qbase + (size_t)(row0 + lr) * DD + g * 8);
    bf16x8 aq1 = *(const bf16x8*)(qbase + (size_t)(row0 + lr) * DD + 32 + g * 8);
    __syncthreads();

    for (int it = 0; it < 8; ++it) {
        f32x4 acc[16] = {};
        __builtin_amdgcn_s_setprio(1);
#pragma unroll
        for (int nf = 0; nf < 16; ++nf) {
            bf16x8 b0 = *(const bf16x8*)&KPs[nf * 16 + lr][g * 8];
            bf16x8 b1 = *(const bf16x8*)&KPs[nf * 16 + lr][32 + g * 8];
            acc[nf] = __builtin_amdgcn_mfma_f32_16x16x32_bf16(aq0, b0, acc[nf], 0, 0, 0);
            acc[nf] = __builtin_amdgcn_mfma_f32_16x16x32_bf16(aq1, b1, acc[nf], 0, 0, 0);
        }
        __builtin_amdgcn_s_setprio(0);

        bf16x8 aqn0 = aq0, aqn1 = aq1;
        if (it < 7) {
            const bf16* qr = qbase + (size_t)(row0 + 128 + lr) * DD;
            aqn0 = *(const bf16x8*)(qr + g * 8);
            aqn1 = *(const bf16x8*)(qr + 32 + g * 8);
        }

        float rs[4];
#pragma unroll
        for (int i = 0; i < 4; ++i) {
            float s = 0.f;
#pragma unroll
            for (int nf = 0; nf < 16; ++nf) {
                float pv = exp2f(acc[nf][i]);
                acc[nf][i] = pv;
                s += pv;
            }
#pragma unroll
            for (int msk = 1; msk < 16; msk <<= 1) s += __shfl_xor(s, msk, 64);
            rs[i] = 1.f / s;
        }

#pragma unroll
        for (int nf = 0; nf < 16; ++nf)
#pragma unroll
            for (int i = 0; i < 4; ++i)
                Ps[wv][4 * g + i][nf * 16 + lr] = (bf16)acc[nf][i];
        __builtin_amdgcn_wave_barrier();

        f32x4 o[4] = {};
        __builtin_amdgcn_s_setprio(1);
#pragma unroll
        for (int ks = 0; ks < 8; ++ks) {
            bf16x8 pa = *(const bf16x8*)&Ps[wv][lr][ks * 32 + g * 8];
#pragma unroll
            for (int n = 0; n < 4; ++n) {
                bf16x8 vb = *(const bf16x8*)&VPs[n * 16 + lr][ks * 32 + g * 8];
                o[n] = __builtin_amdgcn_mfma_f32_16x16x32_bf16(pa, vb, o[n], 0, 0, 0);
            }
        }
        __builtin_amdgcn_s_setprio(0);
        __builtin_amdgcn_wave_barrier();

#pragma unroll
        for (int n = 0; n < 4; ++n)
#pragma unroll
            for (int i = 0; i < 4; ++i)
                Ps[wv][4 * g + i][n * 16 + lr] = (bf16)(o[n][i] * rs[i]);
        __builtin_amdgcn_wave_barrier();
        bf16* crow = ctx + (size_t)(b * SS + row0) * DD + h * DK;
#pragma unroll
        for (int p = 0; p < 2; ++p) {
            int r = p * 8 + (lane >> 3), c = (lane & 7) * 8;
            bf16x8 ov = *(const bf16x8*)&Ps[wv][r][c];
            *(bf16x8*)(crow + (size_t)r * DD + c) = ov;
        }
        __builtin_amdgcn_wave_barrier();

        aq0 = aqn0; aq1 = aqn1;
        row0 += 128;
    }
}

// ---------------------------------------------------------------------------
extern "C" void kernel_launch(void* const* d_in, const int* in_sizes, int n_in,
                              void* d_out, int out_size, void* d_ws, size_t ws_size,
                              hipStream_t stream)
{
    const float* query = (const float*)d_in[0];
    const float* key   = (const float*)d_in[1];
    const float* value = (const float*)d_in[2];
    const float* Wq = (const float*)d_in[3];  const float* bq = (const float*)d_in[4];
    const float* Wk = (const float*)d_in[5];  const float* bk = (const float*)d_in[6];
    const float* Wv = (const float*)d_in[7];  const float* bv = (const float*)d_in[8];
    const float* Wo = (const float*)d_in[9];  const float* bo = (const float*)d_in[10];
    const float* E  = (const float*)d_in[11];
    const float* F  = (const float*)d_in[12];

    char* w = (char*)d_ws;
    size_t off = 0;
    auto alloc = [&](size_t bytes) -> char* {
        char* p = w + off;
        off += (bytes + 255) & ~(size_t)255;
        return p;
    };

    const size_t DW   = (size_t)DD * DD;           // 1M
    const size_t BSD  = (size_t)BB * SS * DD;      // 16.78M
    const size_t BHDR = (size_t)BB * HH * DK * RR; // 4.19M

    bf16* wqb = (bf16*)alloc(DW * 2);
    bf16* wkb = (bf16*)alloc(DW * 2);
    bf16* wvb = (bf16*)alloc(DW * 2);
    bf16* wob = (bf16*)alloc(DW * 2);
    bf16* scr1 = (bf16*)alloc(BSD * 2);            // scratch: kpf/vpf
    bf16* scr2 = (bf16*)alloc(BSD * 2);            // scratch: kpt/vpbb
    bf16* scr3 = (bf16*)alloc(BSD * 2);            // scratch: ctx
    bf16* qbuf = (bf16*)alloc(BSD * 2);
    bf16* kbuf = (bf16*)alloc(BSD * 2);
    bf16* vbuf = (bf16*)alloc(BSD * 2);
    if (off > ws_size) return;

    float* kpf  = (float*)scr1;                    // BHDR f32
    float* vpf  = kpf + BHDR;                      // BHDR f32
    bf16*  kpt  = (bf16*)scr2;                     // BHDR bf16 [B,H,R,DK]
    bf16*  vpbb = kpt + BHDR;                      // BHDR bf16 [B,H,DK,R]
    bf16*  ctx  = (bf16*)scr3;                     // BSD bf16

    // 1. weight converts only (activation converts fused into gemm_qkv)
    cvt_f32_bf16<<<(int)(DW / 2048), 256, 0, stream>>>(Wq, wqb, (int)DW);
    cvt_f32_bf16<<<(int)(DW / 2048), 256, 0, stream>>>(Wk, wkb, (int)DW);
    cvt_f32_bf16<<<(int)(DW / 2048), 256, 0, stream>>>(Wv, wvb, (int)DW);
    cvt_f32_bf16<<<(int)(DW / 2048), 256, 0, stream>>>(Wo, wob, (int)DW);

    // 2. QKV projections: f32 inputs read directly, cvt fused in staging
    const int nwg = ((BB * SS) / 256) * (DD / 128);   // 512, % 8 == 0
    gemm_qkv<<<nwg, 512, 0, stream>>>(query, wqb, bq, qbuf, BB * SS, DD, DD, QSCALE);
    gemm_qkv<<<nwg, 512, 0, stream>>>(key,   wkb, bk, kbuf, BB * SS, DD, DD, 1.0f);
    gemm_qkv<<<nwg, 512, 0, stream>>>(value, wvb, bv, vbuf, BB * SS, DD, DD, 1.0f);

    // 3. kp/vp = k^T E, v^T F — E/F read directly as f32 (fused transpose+cvt)
    hipMemsetAsync(kpf, 0, BHDR * 4 * 2, stream);
    kpvp_gemm<<<dim3(SS / 512, HH, BB), 256, 0, stream>>>(kbuf, E, kpf);
    kpvp_gemm<<<dim3(SS / 512, HH, BB), 256, 0, stream>>>(vbuf, F, vpf);

    // 4. kp -> kpT bf16 [B,H,R,DK]; vp -> bf16 [B,H,DK,R]
    dim3 tb(64, 4);
    transpose_cvt<<<dim3(RR / 64, DK / 64, BB * HH), tb, 0, stream>>>(kpf, kpt, DK, RR);
    cvt_f32_bf16<<<(int)(BHDR / 2048), 256, 0, stream>>>(vpf, vpbb, (int)BHDR);

    // 5. fused softmax attention
    attn_fused<<<dim3(SS / 1024, HH, BB), 512, 0, stream>>>(qbuf, kpt, vpbb, ctx);

    // 6. output projection -> f32 d_out
    gemm_bt<<<nwg, 512, 0, stream>>>(ctx, wob, bo, (float*)d_out, BB * SS, DD, DD, 1.0f);
}

// Round 13
// 497.525 us; speedup vs baseline: 2.1712x; 1.8101x over previous
//
#include <hip/hip_runtime.h>

// ---------------------------------------------------------------------------
// LinearAttention (Linformer-style) on MI355X, bf16 MFMA pipeline, f32 accum.
// B=4 S=4096 D=1024 H=16 R=256 DK=64
// Round 13: gemm_qkv v3 — A staged as f32 via global_load_lds (NO persistent
//           staging regs -> no spill possible), f32->bf16 cvt at fragment
//           read (per-mm scoped). 80KB LDS, VMW5, launch_bounds(512,3).
//           r12's spill: reg budget 128 (bounds 512/4) < acc64+staging80.
// ---------------------------------------------------------------------------

typedef __bf16 bf16;
typedef bf16 bf16x8 __attribute__((ext_vector_type(8)));
typedef bf16 bf16x4 __attribute__((ext_vector_type(4)));
typedef float f32x4 __attribute__((ext_vector_type(4)));

constexpr int BB = 4, SS = 4096, DD = 1024, HH = 16, RR = 256, DK = 64;

// q-projection output pre-scale: logits*log2e/8 so softmax uses exp2 directly
#define QSCALE 0.1803368801111204f

// async global->LDS, 16B per lane. ldsbase must be wave-uniform; HW writes
// lane l's 16B at ldsbase + l*16. gptr is per-lane.
__device__ __forceinline__ void gl2lds16(const void* g, void* l, int lane)
{
#if __has_builtin(__builtin_amdgcn_global_load_lds)
    auto gp = reinterpret_cast<const __attribute__((address_space(1))) void*>(
        reinterpret_cast<uintptr_t>(g));
    auto lp = reinterpret_cast<__attribute__((address_space(3))) void*>(
        reinterpret_cast<uintptr_t>(l));
    __builtin_amdgcn_global_load_lds(gp, lp, 16, 0, 0);
    (void)lane;
#else
    *(bf16x8*)((char*)l + lane * 16) = *(const bf16x8*)g;
#endif
}

#define VMW5  asm volatile("s_waitcnt vmcnt(5)" ::: "memory")
#define VMW3  asm volatile("s_waitcnt vmcnt(3)" ::: "memory")
#define VMW0  asm volatile("s_waitcnt vmcnt(0)" ::: "memory")
#define LGKM0 asm volatile("s_waitcnt lgkmcnt(0)" ::: "memory")

// ---------------------------------------------------------------------------
// Elementwise f32 -> bf16 convert, 8 elems/thread (weights + vp only)
// ---------------------------------------------------------------------------
__global__ void cvt_f32_bf16(const float* __restrict__ in, bf16* __restrict__ out, int n)
{
    int i = (blockIdx.x * 256 + threadIdx.x) * 8;
    if (i < n) {
        float4 v0 = *(const float4*)(in + i);
        float4 v1 = *(const float4*)(in + i + 4);
        bf16x8 h;
        h[0] = (bf16)v0.x; h[1] = (bf16)v0.y; h[2] = (bf16)v0.z; h[3] = (bf16)v0.w;
        h[4] = (bf16)v1.x; h[5] = (bf16)v1.y; h[6] = (bf16)v1.z; h[7] = (bf16)v1.w;
        *(bf16x8*)(out + i) = h;
    }
}

// ---------------------------------------------------------------------------
// Tiled transpose + convert (used for kp f32 [DK,R] -> kpT bf16 [R,DK])
// ---------------------------------------------------------------------------
__global__ void transpose_cvt(const float* __restrict__ in, bf16* __restrict__ out,
                              int rows, int cols)
{
    __shared__ float t[64][65];
    const float* I = in + (size_t)blockIdx.z * rows * cols;
    bf16* O = out + (size_t)blockIdx.z * rows * cols;
    int c0 = blockIdx.x * 64, r0 = blockIdx.y * 64;
    int tx = threadIdx.x, ty = threadIdx.y;
#pragma unroll
    for (int i = ty; i < 64; i += 4)
        t[i][tx] = I[(size_t)(r0 + i) * cols + c0 + tx];
    __syncthreads();
#pragma unroll
    for (int i = ty; i < 64; i += 4)
        O[(size_t)(c0 + i) * rows + r0 + tx] = (bf16)t[tx][i];
}

// ---------------------------------------------------------------------------
// gemm_qkv v3: C[M,N](bf16) = (A_f32[M,K] * W_bf16[N,K]^T + bias) * oscale.
// K==1024. 256x128 tile, BK=32, 8 waves, LDS 80KB:
//   Asf f32 [2][256][32] (64KB, gload_lds-staged, chunk16B ^= row&7 swizzle)
//   Bs  bf16 [2][128][32] (16KB, as in gemm_bt)
// Fragment read converts f32->bf16 in regs (per-mm scoped transients).
// 5 vm ops/tile (4 A + 1 B) -> steady VMW5 drains exactly tile t+1.
// launch_bounds(512,3): reg cap 170 -> cannot spill (need ~145 incl acc).
// ---------------------------------------------------------------------------
__global__ __launch_bounds__(512, 3) void gemm_qkv(const float* __restrict__ A,
                                                   const bf16* __restrict__ W,
                                                   const float* __restrict__ bias,
                                                   bf16* __restrict__ Cp,
                                                   int M, int N, int K, float oscale)
{
    __shared__ float Asf[2][256][32];
    __shared__ bf16 Bs[2][128][32];
    const int tid = threadIdx.x, wv = tid >> 6, lane = tid & 63;
    const int g = lane >> 4, lr = lane & 15;

    const int nwg = gridDim.x;
    const int cpx = nwg >> 3;                      // nwg % 8 == 0 (bijective)
    const int bid = blockIdx.x;
    const int swz = (bid & 7) * cpx + (bid >> 3);
    const int gx = N >> 7;
    const int mt = swz / gx, nt = swz % gx;
    const int m0 = mt * 256, n0 = nt * 128;
    const int wm = (wv >> 1) * 64, wn = (wv & 1) * 64;

    // B staging (gload_lds): row = wv*16 + lane>>2, source slot pre-swizzled
    const int srow = lane >> 2;
    const int scol = ((lane & 3) ^ ((lane >> 4) & 3)) * 8;
    // A staging (gload_lds, f32): window = 8 rows x 128B; lane covers
    // row lane>>3, phys chunk lane&7; source chunk pre-swizzled by row&7.
    const int arow = lane >> 3;
    const int acol = ((lane & 7) ^ (arow & 7)) * 4;   // f32 units

    f32x4 acc[4][4] = {};

    auto stageA = [&](int buf, int tk) {           // 32 windows, 4 per wave
#pragma unroll
        for (int j = 0; j < 4; ++j) {
            int rowbase = (wv * 4 + j) * 8;
            gl2lds16(A + (size_t)(m0 + rowbase + arow) * 1024 + tk * 32 + acol,
                     &Asf[buf][rowbase][0], lane);
        }
    };
    auto stageB = [&](int buf, int tk) {
        gl2lds16(W + (size_t)(n0 + wv * 16 + srow) * 1024 + tk * 32 + scol,
                 &Bs[buf][wv * 16][0], lane);
    };

#define PHQ(PB, STAGE_STMT, VM_STMT)                                             \
    {                                                                            \
        const int so = (g ^ (lr >> 2)) << 4;                                     \
        bf16x8 aF[4], bF[4];                                                     \
        _Pragma("unroll") for (int mm = 0; mm < 4; ++mm) {                       \
            const char* ar_ = (const char*)&Asf[PB][wm + mm * 16 + lr][0];       \
            float4 lo_ = *(const float4*)(ar_ + (((2 * g) ^ (lr & 7)) << 4));    \
            float4 hi_ = *(const float4*)(ar_ + (((2 * g + 1) ^ (lr & 7)) << 4));\
            bf16x8 t_;                                                           \
            t_[0] = (bf16)lo_.x; t_[1] = (bf16)lo_.y;                            \
            t_[2] = (bf16)lo_.z; t_[3] = (bf16)lo_.w;                            \
            t_[4] = (bf16)hi_.x; t_[5] = (bf16)hi_.y;                            \
            t_[6] = (bf16)hi_.z; t_[7] = (bf16)hi_.w;                            \
            aF[mm] = t_;                                                         \
        }                                                                        \
        _Pragma("unroll") for (int nn = 0; nn < 4; ++nn)                         \
            bF[nn] = *(const bf16x8*)((const char*)&Bs[PB][wn + nn * 16 + lr][0] + so); \
        LGKM0;                                                                   \
        __builtin_amdgcn_s_barrier();              /* reads done, bufs free */   \
        STAGE_STMT;                                /* tile t+2: 4 A + 1 B */     \
        VM_STMT;                                   /* drain tile t+1 (5 ops) */  \
        __builtin_amdgcn_s_barrier();              /* t+1 buffer ready */        \
        __builtin_amdgcn_sched_barrier(0);                                       \
        __builtin_amdgcn_s_setprio(1);                                           \
        _Pragma("unroll") for (int mm = 0; mm < 4; ++mm) {                       \
            _Pragma("unroll") for (int nn = 0; nn < 4; ++nn) {                   \
                acc[mm][nn] = __builtin_amdgcn_mfma_f32_16x16x32_bf16(           \
                    aF[mm], bF[nn], acc[mm][nn], 0, 0, 0); } }                   \
        __builtin_amdgcn_s_setprio(0);                                           \
    }

    // prologue: stage tiles 0,1 (10 ops); VMW5 drains tile0, keeps tile1
    stageA(0, 0); stageB(0, 0);
    stageA(1, 1); stageB(1, 1);
    VMW5;
    __builtin_amdgcn_s_barrier();

#pragma unroll 1
    for (int t = 0; t < 30; ++t) {                 // K/32 = 32 tiles
        const int pb = t & 1;
        PHQ(pb, { stageA(pb, t + 2); stageB(pb, t + 2); }, VMW5);
    }
    PHQ(0, (void)0, VMW0);                         // tile 30
    PHQ(1, (void)0, (void)0);                      // tile 31
#undef PHQ

    float bv[4];
#pragma unroll
    for (int n = 0; n < 4; ++n) bv[n] = bias[n0 + wn + n * 16 + lr];

    // bounce through LDS (swizzled, 4KB/wave inside Asf) -> coalesced stores
    char* myb = (char*)&Asf[0][0][0] + wv * 4096;
#pragma unroll
    for (int mh = 0; mh < 2; ++mh) {
#pragma unroll
        for (int mm = 0; mm < 2; ++mm)
#pragma unroll
            for (int n = 0; n < 4; ++n) {
                int colb = (n * 16 + lr) * 2;
#pragma unroll
                for (int i = 0; i < 4; ++i) {
                    int row = mm * 16 + 4 * g + i;
                    *(bf16*)(myb + row * 128 + (colb ^ ((row & 7) << 4))) =
                        (bf16)((acc[mh * 2 + mm][n][i] + bv[n]) * oscale);
                }
            }
        __builtin_amdgcn_wave_barrier();
        bf16* Cb = Cp + (size_t)(m0 + wm + mh * 32) * N + n0 + wn;
#pragma unroll
        for (int it = 0; it < 4; ++it) {
            int r = it * 8 + (lane >> 3);
            int sl = lane & 7;
            bf16x8 vv = *(const bf16x8*)(myb + r * 128 + ((sl ^ (r & 7)) << 4));
            *(bf16x8*)(Cb + (size_t)r * N + sl * 8) = vv;
        }
        __builtin_amdgcn_wave_barrier();
    }
}

// ---------------------------------------------------------------------------
// gemm_bt (round-8 structure, frozen): bf16 A, f32 out — Wo projection only.
// ---------------------------------------------------------------------------
__global__ __launch_bounds__(512, 4) void gemm_bt(const bf16* __restrict__ A,
                                                  const bf16* __restrict__ W,
                                                  const float* __restrict__ bias,
                                                  float* __restrict__ Cp,
                                                  int M, int N, int K, float oscale)
{
    __shared__ bf16 As[2][256][32];
    __shared__ bf16 Bs[2][128][32];
    const int tid = threadIdx.x, wv = tid >> 6, lane = tid & 63;
    const int g = lane >> 4, lr = lane & 15;

    const int nwg = gridDim.x;
    const int cpx = nwg >> 3;
    const int bid = blockIdx.x;
    const int swz = (bid & 7) * cpx + (bid >> 3);
    const int gx = N >> 7;
    const int mt = swz / gx, nt = swz % gx;
    const int m0 = mt * 256, n0 = nt * 128;
    const int wm = (wv >> 1) * 64, wn = (wv & 1) * 64;

    const int srow = lane >> 2;
    const int scol = ((lane & 3) ^ ((lane >> 4) & 3)) * 8;

    f32x4 acc[4][4] = {};

    auto stageA = [&](int buf, int tk) {
#pragma unroll
        for (int s2 = 0; s2 < 2; ++s2) {
            int c = wv * 2 + s2;
            gl2lds16(A + (size_t)(m0 + c * 16 + srow) * 1024 + tk * 32 + scol,
                     &As[buf][c * 16][0], lane);
        }
    };
    auto stageB = [&](int buf, int tk) {
        gl2lds16(W + (size_t)(n0 + wv * 16 + srow) * 1024 + tk * 32 + scol,
                 &Bs[buf][wv * 16][0], lane);
    };

#define PHK(PB, STAGE_STMT, VM_STMT)                                             \
    {                                                                            \
        const int so = (g ^ (lr >> 2)) << 4;                                     \
        bf16x8 aF[4], bF[4];                                                     \
        _Pragma("unroll") for (int mm = 0; mm < 4; ++mm)                         \
            aF[mm] = *(const bf16x8*)((const char*)&As[PB][wm + mm * 16 + lr][0] + so); \
        _Pragma("unroll") for (int nn = 0; nn < 4; ++nn)                         \
            bF[nn] = *(const bf16x8*)((const char*)&Bs[PB][wn + nn * 16 + lr][0] + so); \
        LGKM0;                                                                   \
        __builtin_amdgcn_s_barrier();                                            \
        STAGE_STMT;                                                              \
        VM_STMT;                                                                 \
        __builtin_amdgcn_s_barrier();                                            \
        __builtin_amdgcn_sched_barrier(0);                                       \
        __builtin_amdgcn_s_setprio(1);                                           \
        _Pragma("unroll") for (int mm = 0; mm < 4; ++mm) {                       \
            _Pragma("unroll") for (int nn = 0; nn < 4; ++nn) {                   \
                acc[mm][nn] = __builtin_amdgcn_mfma_f32_16x16x32_bf16(           \
                    aF[mm], bF[nn], acc[mm][nn], 0, 0, 0); } }                   \
        __builtin_amdgcn_s_setprio(0);                                           \
    }

    stageA(0, 0); stageB(0, 0);
    stageA(1, 1); stageB(1, 1);
    VMW3;
    __builtin_amdgcn_s_barrier();

#pragma unroll 1
    for (int t = 0; t < 30; ++t) {
        const int pb = t & 1;
        PHK(pb, { stageA(pb, t + 2); stageB(pb, t + 2); }, VMW3);
    }
    PHK(0, (void)0, VMW0);
    PHK(1, (void)0, (void)0);
#undef PHK

    float bv[4];
#pragma unroll
    for (int n = 0; n < 4; ++n) bv[n] = bias[n0 + wn + n * 16 + lr];

#pragma unroll
    for (int n = 0; n < 4; ++n) {
        int col = n0 + wn + n * 16 + lr;
#pragma unroll
        for (int m = 0; m < 4; ++m) {
            int row = m0 + wm + m * 16 + 4 * g;
#pragma unroll
            for (int i = 0; i < 4; ++i)
                Cp[(size_t)(row + i) * N + col] = (acc[m][n][i] + bv[n]) * oscale;
        }
    }
}

// ---------------------------------------------------------------------------
// kp[b,h,d,r] += sum_{s in chunk} X[b,s,h*64+d] * E[h,s,r]
// E read DIRECTLY as f32 [H,S,R] (fused transpose+convert in registers).
// ---------------------------------------------------------------------------
__global__ __launch_bounds__(256) void kpvp_gemm(const bf16* __restrict__ X,
                                                 const float* __restrict__ E,
                                                 float* __restrict__ out)
{
    __shared__ bf16 Ak[64][40];
    const int b = blockIdx.z, h = blockIdx.y;
    const int s0 = blockIdx.x * 512;
    const int tid = threadIdx.x, wv = tid >> 6, lane = tid & 63;
    const int g = lane >> 4, lr = lane & 15;
    const float* Eh = E + (size_t)h * SS * RR;
    const int rbase = wv * 64 + lr;
    f32x4 acc[4][4] = {};

    for (int kt = 0; kt < 512; kt += 32) {
        const int sb = s0 + kt;
        __syncthreads();
        float ef[4][8];
        const float* Eb = Eh + (size_t)(sb + g * 8) * RR + rbase;
#pragma unroll
        for (int n = 0; n < 4; ++n)
#pragma unroll
            for (int j = 0; j < 8; ++j)
                ef[n][j] = Eb[(size_t)j * RR + n * 16];
        {
            int sl = tid >> 3, dblk = (tid & 7) * 8;
            bf16x8 v = *(const bf16x8*)(X + ((size_t)b * SS + sb + sl) * DD + h * DK + dblk);
#pragma unroll
            for (int j = 0; j < 8; ++j) Ak[dblk + j][sl] = v[j];
        }
        bf16x8 bb[4];
#pragma unroll
        for (int n = 0; n < 4; ++n)
#pragma unroll
            for (int j = 0; j < 8; ++j)
                bb[n][j] = (bf16)ef[n][j];
        __syncthreads();

        bf16x8 a[4];
#pragma unroll
        for (int m = 0; m < 4; ++m) a[m] = *(const bf16x8*)&Ak[m * 16 + lr][g * 8];
#pragma unroll
        for (int m = 0; m < 4; ++m)
#pragma unroll
            for (int n = 0; n < 4; ++n)
                acc[m][n] = __builtin_amdgcn_mfma_f32_16x16x32_bf16(a[m], bb[n], acc[m][n], 0, 0, 0);
    }

    float* o = out + ((size_t)(b * HH + h)) * DK * RR;
#pragma unroll
    for (int m = 0; m < 4; ++m)
#pragma unroll
        for (int n = 0; n < 4; ++n) {
            int r = wv * 64 + n * 16 + lr;
#pragma unroll
            for (int i = 0; i < 4; ++i)
                atomicAdd(o + (size_t)(m * 16 + 4 * g + i) * RR + r, acc[m][n][i]);
        }
}

// ---------------------------------------------------------------------------
// Fused attention (round-8 structure, frozen at 57us).
// ---------------------------------------------------------------------------
__global__ __launch_bounds__(512) void attn_fused(const bf16* __restrict__ qb,
                                                  const bf16* __restrict__ kpt,
                                                  const bf16* __restrict__ vpb,
                                                  bf16* __restrict__ ctx)
{
    __shared__ bf16 KPs[256][72];
    __shared__ bf16 VPs[64][264];
    __shared__ bf16 Ps[8][16][264];
    const int b = blockIdx.z, h = blockIdx.y, qt = blockIdx.x;
    const int tid = threadIdx.x, wv = tid >> 6, lane = tid & 63;
    const int g = lane >> 4, lr = lane & 15;
    const bf16* kph = kpt + ((size_t)(b * HH + h)) * RR * DK;
    const bf16* vph = vpb + ((size_t)(b * HH + h)) * DK * RR;

#pragma unroll
    for (int p = 0; p < 4; ++p) {
        int f = p * 512 + tid;
        *(bf16x8*)&KPs[f >> 3][(f & 7) * 8] = *(const bf16x8*)(kph + (size_t)f * 8);
        *(bf16x8*)&VPs[f >> 5][(f & 31) * 8] = *(const bf16x8*)(vph + (size_t)f * 8);
    }

    const bf16* qbase = qb + (size_t)b * SS * DD + h * DK;
    int row0 = qt * 1024 + wv * 16;
    bf16x8 aq0 = *(const bf16x8*)(qbase + (size_t)(row0 + lr) * DD + g * 8);
    bf16x8 aq1 = *(const bf16x8*)(qbase + (size_t)(row0 + lr) * DD + 32 + g * 8);
    __syncthreads();

    for (int it = 0; it < 8; ++it) {
        f32x4 acc[16] = {};
        __builtin_amdgcn_s_setprio(1);
#pragma unroll
        for (int nf = 0; nf < 16; ++nf) {
            bf16x8 b0 = *(const bf16x8*)&KPs[nf * 16 + lr][g * 8];
            bf16x8 b1 = *(const bf16x8*)&KPs[nf * 16 + lr][32 + g * 8];
            acc[nf] = __builtin_amdgcn_mfma_f32_16x16x32_bf16(aq0, b0, acc[nf], 0, 0, 0);
            acc[nf] = __builtin_amdgcn_mfma_f32_16x16x32_bf16(aq1, b1, acc[nf], 0, 0, 0);
        }
        __builtin_amdgcn_s_setprio(0);

        bf16x8 aqn0 = aq0, aqn1 = aq1;
        if (it < 7) {
            const bf16* qr = qbase + (size_t)(row0 + 128 + lr) * DD;
            aqn0 = *(const bf16x8*)(qr + g * 8);
            aqn1 = *(const bf16x8*)(qr + 32 + g * 8);
        }

        float rs[4];
#pragma unroll
        for (int i = 0; i < 4; ++i) {
            float s = 0.f;
#pragma unroll
            for (int nf = 0; nf < 16; ++nf) {
                float pv = exp2f(acc[nf][i]);
                acc[nf][i] = pv;
                s += pv;
            }
#pragma unroll
            for (int msk = 1; msk < 16; msk <<= 1) s += __shfl_xor(s, msk, 64);
            rs[i] = 1.f / s;
        }

#pragma unroll
        for (int nf = 0; nf < 16; ++nf)
#pragma unroll
            for (int i = 0; i < 4; ++i)
                Ps[wv][4 * g + i][nf * 16 + lr] = (bf16)acc[nf][i];
        __builtin_amdgcn_wave_barrier();

        f32x4 o[4] = {};
        __builtin_amdgcn_s_setprio(1);
#pragma unroll
        for (int ks = 0; ks < 8; ++ks) {
            bf16x8 pa = *(const bf16x8*)&Ps[wv][lr][ks * 32 + g * 8];
#pragma unroll
            for (int n = 0; n < 4; ++n) {
                bf16x8 vb = *(const bf16x8*)&VPs[n * 16 + lr][ks * 32 + g * 8];
                o[n] = __builtin_amdgcn_mfma_f32_16x16x32_bf16(pa, vb, o[n], 0, 0, 0);
            }
        }
        __builtin_amdgcn_s_setprio(0);
        __builtin_amdgcn_wave_barrier();

#pragma unroll
        for (int n = 0; n < 4; ++n)
#pragma unroll
            for (int i = 0; i < 4; ++i)
                Ps[wv][4 * g + i][n * 16 + lr] = (bf16)(o[n][i] * rs[i]);
        __builtin_amdgcn_wave_barrier();
        bf16* crow = ctx + (size_t)(b * SS + row0) * DD + h * DK;
#pragma unroll
        for (int p = 0; p < 2; ++p) {
            int r = p * 8 + (lane >> 3), c = (lane & 7) * 8;
            bf16x8 ov = *(const bf16x8*)&Ps[wv][r][c];
            *(bf16x8*)(crow + (size_t)r * DD + c) = ov;
        }
        __builtin_amdgcn_wave_barrier();

        aq0 = aqn0; aq1 = aqn1;
        row0 += 128;
    }
}

// ---------------------------------------------------------------------------
extern "C" void kernel_launch(void* const* d_in, const int* in_sizes, int n_in,
                              void* d_out, int out_size, void* d_ws, size_t ws_size,
                              hipStream_t stream)
{
    const float* query = (const float*)d_in[0];
    const float* key   = (const float*)d_in[1];
    const float* value = (const float*)d_in[2];
    const float* Wq = (const float*)d_in[3];  const float* bq = (const float*)d_in[4];
    const float* Wk = (const float*)d_in[5];  const float* bk = (const float*)d_in[6];
    const float* Wv = (const float*)d_in[7];  const float* bv = (const float*)d_in[8];
    const float* Wo = (const float*)d_in[9];  const float* bo = (const float*)d_in[10];
    const float* E  = (const float*)d_in[11];
    const float* F  = (const float*)d_in[12];

    char* w = (char*)d_ws;
    size_t off = 0;
    auto alloc = [&](size_t bytes) -> char* {
        char* p = w + off;
        off += (bytes + 255) & ~(size_t)255;
        return p;
    };

    const size_t DW   = (size_t)DD * DD;           // 1M
    const size_t BSD  = (size_t)BB * SS * DD;      // 16.78M
    const size_t BHDR = (size_t)BB * HH * DK * RR; // 4.19M

    bf16* wqb = (bf16*)alloc(DW * 2);
    bf16* wkb = (bf16*)alloc(DW * 2);
    bf16* wvb = (bf16*)alloc(DW * 2);
    bf16* wob = (bf16*)alloc(DW * 2);
    bf16* scr1 = (bf16*)alloc(BSD * 2);            // scratch: kpf/vpf
    bf16* scr2 = (bf16*)alloc(BSD * 2);            // scratch: kpt/vpbb
    bf16* scr3 = (bf16*)alloc(BSD * 2);            // scratch: ctx
    bf16* qbuf = (bf16*)alloc(BSD * 2);
    bf16* kbuf = (bf16*)alloc(BSD * 2);
    bf16* vbuf = (bf16*)alloc(BSD * 2);
    if (off > ws_size) return;

    float* kpf  = (float*)scr1;                    // BHDR f32
    float* vpf  = kpf + BHDR;                      // BHDR f32
    bf16*  kpt  = (bf16*)scr2;                     // BHDR bf16 [B,H,R,DK]
    bf16*  vpbb = kpt + BHDR;                      // BHDR bf16 [B,H,DK,R]
    bf16*  ctx  = (bf16*)scr3;                     // BSD bf16

    // 1. weight converts only (activation converts fused into gemm_qkv)
    cvt_f32_bf16<<<(int)(DW / 2048), 256, 0, stream>>>(Wq, wqb, (int)DW);
    cvt_f32_bf16<<<(int)(DW / 2048), 256, 0, stream>>>(Wk, wkb, (int)DW);
    cvt_f32_bf16<<<(int)(DW / 2048), 256, 0, stream>>>(Wv, wvb, (int)DW);
    cvt_f32_bf16<<<(int)(DW / 2048), 256, 0, stream>>>(Wo, wob, (int)DW);

    // 2. QKV projections: f32 inputs staged directly to LDS, cvt at read
    const int nwg = ((BB * SS) / 256) * (DD / 128);   // 512, % 8 == 0
    gemm_qkv<<<nwg, 512, 0, stream>>>(query, wqb, bq, qbuf, BB * SS, DD, DD, QSCALE);
    gemm_qkv<<<nwg, 512, 0, stream>>>(key,   wkb, bk, kbuf, BB * SS, DD, DD, 1.0f);
    gemm_qkv<<<nwg, 512, 0, stream>>>(value, wvb, bv, vbuf, BB * SS, DD, DD, 1.0f);

    // 3. kp/vp = k^T E, v^T F — E/F read directly as f32 (fused transpose+cvt)
    hipMemsetAsync(kpf, 0, BHDR * 4 * 2, stream);
    kpvp_gemm<<<dim3(SS / 512, HH, BB), 256, 0, stream>>>(kbuf, E, kpf);
    kpvp_gemm<<<dim3(SS / 512, HH, BB), 256, 0, stream>>>(vbuf, F, vpf);

    // 4. kp -> kpT bf16 [B,H,R,DK]; vp -> bf16 [B,H,DK,R]
    dim3 tb(64, 4);
    transpose_cvt<<<dim3(RR / 64, DK / 64, BB * HH), tb, 0, stream>>>(kpf, kpt, DK, RR);
    cvt_f32_bf16<<<(int)(BHDR / 2048), 256, 0, stream>>>(vpf, vpbb, (int)BHDR);

    // 5. fused softmax attention
    attn_fused<<<dim3(SS / 1024, HH, BB), 512, 0, stream>>>(qbuf, kpt, vpbb, ctx);

    // 6. output projection -> f32 d_out
    gemm_bt<<<nwg, 512, 0, stream>>>(ctx, wob, bo, (float*)d_out, BB * SS, DD, DD, 1.0f);
}

// Round 14
// 414.719 us; speedup vs baseline: 2.6047x; 1.1997x over previous
//
#include <hip/hip_runtime.h>

// ---------------------------------------------------------------------------
// LinearAttention (Linformer-style) on MI355X, bf16 MFMA pipeline, f32 accum.
// B=4 S=4096 D=1024 H=16 R=256 DK=64
// Round 14: full revert to r10 pipeline (convert-fusion abandoned after 3
//           failures) + ONE change: gemm_bt fragment prefetch — frags for
//           tile t+1 read AFTER the barrier (fly during MFMA(t)), drained by
//           the next phase's lgkm0. Two named frag sets (X/Y), unroll x2.
//           launch_bounds(512,2): ~150 VGPR, no spill, 1 block/CU.
// ---------------------------------------------------------------------------

typedef __bf16 bf16;
typedef bf16 bf16x8 __attribute__((ext_vector_type(8)));
typedef bf16 bf16x4 __attribute__((ext_vector_type(4)));
typedef float f32x4 __attribute__((ext_vector_type(4)));

constexpr int BB = 4, SS = 4096, DD = 1024, HH = 16, RR = 256, DK = 64;

// q-projection output pre-scale: logits*log2e/8 so softmax uses exp2 directly
#define QSCALE 0.1803368801111204f

// async global->LDS, 16B per lane. ldsbase must be wave-uniform; HW writes
// lane l's 16B at ldsbase + l*16. gptr is per-lane.
__device__ __forceinline__ void gl2lds16(const void* g, void* l, int lane)
{
#if __has_builtin(__builtin_amdgcn_global_load_lds)
    auto gp = reinterpret_cast<const __attribute__((address_space(1))) void*>(
        reinterpret_cast<uintptr_t>(g));
    auto lp = reinterpret_cast<__attribute__((address_space(3))) void*>(
        reinterpret_cast<uintptr_t>(l));
    __builtin_amdgcn_global_load_lds(gp, lp, 16, 0, 0);
    (void)lane;
#else
    *(bf16x8*)((char*)l + lane * 16) = *(const bf16x8*)g;
#endif
}

#define VMW3  asm volatile("s_waitcnt vmcnt(3)" ::: "memory")
#define VMW0  asm volatile("s_waitcnt vmcnt(0)" ::: "memory")
#define LGKM0 asm volatile("s_waitcnt lgkmcnt(0)" ::: "memory")

// ---------------------------------------------------------------------------
// Elementwise f32 -> bf16 convert, 8 elems/thread
// ---------------------------------------------------------------------------
__global__ void cvt_f32_bf16(const float* __restrict__ in, bf16* __restrict__ out, int n)
{
    int i = (blockIdx.x * 256 + threadIdx.x) * 8;
    if (i < n) {
        float4 v0 = *(const float4*)(in + i);
        float4 v1 = *(const float4*)(in + i + 4);
        bf16x8 h;
        h[0] = (bf16)v0.x; h[1] = (bf16)v0.y; h[2] = (bf16)v0.z; h[3] = (bf16)v0.w;
        h[4] = (bf16)v1.x; h[5] = (bf16)v1.y; h[6] = (bf16)v1.z; h[7] = (bf16)v1.w;
        *(bf16x8*)(out + i) = h;
    }
}

// ---------------------------------------------------------------------------
// Tiled transpose + convert (used for kp f32 [DK,R] -> kpT bf16 [R,DK])
// ---------------------------------------------------------------------------
__global__ void transpose_cvt(const float* __restrict__ in, bf16* __restrict__ out,
                              int rows, int cols)
{
    __shared__ float t[64][65];
    const float* I = in + (size_t)blockIdx.z * rows * cols;
    bf16* O = out + (size_t)blockIdx.z * rows * cols;
    int c0 = blockIdx.x * 64, r0 = blockIdx.y * 64;
    int tx = threadIdx.x, ty = threadIdx.y;
#pragma unroll
    for (int i = ty; i < 64; i += 4)
        t[i][tx] = I[(size_t)(r0 + i) * cols + c0 + tx];
    __syncthreads();
#pragma unroll
    for (int i = ty; i < 64; i += 4)
        O[(size_t)(c0 + i) * rows + r0 + tx] = (bf16)t[tx][i];
}

// ---------------------------------------------------------------------------
// C[M,N] = (A[M,K](bf16) * W[N,K]^T(bf16) + bias[N]) * oscale.   K == 1024.
// 256x128 tile, BK=32, 8 waves (4M x 2N), 48KB LDS, counted VMW3, swizzle.
// r14 pipeline: frags for tile t+1 are read AFTER the phase barrier and fly
// during MFMA(t); they are drained by the NEXT phase's lgkm0 (a full phase
// of latency cover). Zero exposed ds_read on the critical path.
//   phase t: lgkm0 | barrier | stage(buf t%2, t+2) | VMW3 | barrier |
//            read frags(t+1) from buf (t+1)%2 | MFMA(t)
// ---------------------------------------------------------------------------
template <bool OUT_F32>
__global__ __launch_bounds__(512, 2) void gemm_bt(const bf16* __restrict__ A,
                                                  const bf16* __restrict__ W,
                                                  const float* __restrict__ bias,
                                                  void* __restrict__ Cp,
                                                  int M, int N, int K, float oscale)
{
    __shared__ bf16 As[2][256][32];
    __shared__ bf16 Bs[2][128][32];
    const int tid = threadIdx.x, wv = tid >> 6, lane = tid & 63;
    const int g = lane >> 4, lr = lane & 15;

    const int nwg = gridDim.x;
    const int cpx = nwg >> 3;                      // nwg % 8 == 0 (bijective)
    const int bid = blockIdx.x;
    const int swz = (bid & 7) * cpx + (bid >> 3);
    const int gx = N >> 7;
    const int mt = swz / gx, nt = swz % gx;
    const int m0 = mt * 256, n0 = nt * 128;
    const int wm = (wv >> 1) * 64, wn = (wv & 1) * 64;

    const int srow = lane >> 2;
    const int scol = ((lane & 3) ^ ((lane >> 4) & 3)) * 8;
    const int so = (g ^ (lr >> 2)) << 4;

    f32x4 acc[4][4] = {};
    bf16x8 aX[4], bX[4], aY[4], bY[4];             // two frag sets (static idx)

    auto stageA = [&](int buf, int tk) {
#pragma unroll
        for (int s2 = 0; s2 < 2; ++s2) {
            int c = wv * 2 + s2;
            gl2lds16(A + (size_t)(m0 + c * 16 + srow) * 1024 + tk * 32 + scol,
                     &As[buf][c * 16][0], lane);
        }
    };
    auto stageB = [&](int buf, int tk) {
        gl2lds16(W + (size_t)(n0 + wv * 16 + srow) * 1024 + tk * 32 + scol,
                 &Bs[buf][wv * 16][0], lane);
    };

#define RD(aS, bS, PB)                                                           \
    {                                                                            \
        _Pragma("unroll") for (int mm = 0; mm < 4; ++mm)                         \
            aS[mm] = *(const bf16x8*)((const char*)&As[PB][wm + mm * 16 + lr][0] + so); \
        _Pragma("unroll") for (int nn = 0; nn < 4; ++nn)                         \
            bS[nn] = *(const bf16x8*)((const char*)&Bs[PB][wn + nn * 16 + lr][0] + so); \
    }
#define MM(aS, bS)                                                               \
    {                                                                            \
        __builtin_amdgcn_s_setprio(1);                                           \
        _Pragma("unroll") for (int mm = 0; mm < 4; ++mm) {                       \
            _Pragma("unroll") for (int nn = 0; nn < 4; ++nn) {                   \
                acc[mm][nn] = __builtin_amdgcn_mfma_f32_16x16x32_bf16(           \
                    aS[mm], bS[nn], acc[mm][nn], 0, 0, 0); } }                   \
        __builtin_amdgcn_s_setprio(0);                                           \
    }
#define PH(CUR_A, CUR_B, NXT_A, NXT_B, PB, STAGE_STMT, VM_STMT)                  \
    {                                                                            \
        LGKM0;                          /* drain my frags(t) reads */            \
        __builtin_amdgcn_s_barrier();   /* all waves done with buf PB */         \
        STAGE_STMT;                     /* tile t+2 -> buf PB */                 \
        VM_STMT;                        /* drain stage(t+1) */                   \
        __builtin_amdgcn_s_barrier();   /* t+1 visible */                        \
        __builtin_amdgcn_sched_barrier(0);                                       \
        RD(NXT_A, NXT_B, PB ^ 1);       /* frags(t+1) fly during MFMA */         \
        __builtin_amdgcn_sched_barrier(0);                                       \
        MM(CUR_A, CUR_B);                                                        \
    }

    // prologue: stage tiles 0,1; drain tile0; read frags(0) into X
    stageA(0, 0); stageB(0, 0);
    stageA(1, 1); stageB(1, 1);
    VMW3;
    __builtin_amdgcn_s_barrier();
    RD(aX, bX, 0);

#pragma unroll 1
    for (int t = 0; t < 30; t += 2) {              // phases for tiles 0..29
        PH(aX, bX, aY, bY, 0, { stageA(0, t + 2); stageB(0, t + 2); }, VMW3);
        PH(aY, bY, aX, bX, 1, { stageA(1, t + 3); stageB(1, t + 3); }, VMW3);
    }
    PH(aX, bX, aY, bY, 0, (void)0, VMW0);          // tile 30; read frags(31)
    LGKM0;
    MM(aY, bY);                                    // tile 31
#undef PH
#undef MM
#undef RD

    float bv[4];
#pragma unroll
    for (int n = 0; n < 4; ++n) bv[n] = bias[n0 + wn + n * 16 + lr];

    if constexpr (OUT_F32) {
#pragma unroll
        for (int n = 0; n < 4; ++n) {
            int col = n0 + wn + n * 16 + lr;
#pragma unroll
            for (int m = 0; m < 4; ++m) {
                int row = m0 + wm + m * 16 + 4 * g;
#pragma unroll
                for (int i = 0; i < 4; ++i)
                    ((float*)Cp)[(size_t)(row + i) * N + col] = (acc[m][n][i] + bv[n]) * oscale;
            }
        }
    } else {
        char* myb = (char*)&As[0][0][0] + wv * 4096;
#pragma unroll
        for (int mh = 0; mh < 2; ++mh) {
#pragma unroll
            for (int mm = 0; mm < 2; ++mm)
#pragma unroll
                for (int n = 0; n < 4; ++n) {
                    int colb = (n * 16 + lr) * 2;
#pragma unroll
                    for (int i = 0; i < 4; ++i) {
                        int row = mm * 16 + 4 * g + i;
                        *(bf16*)(myb + row * 128 + (colb ^ ((row & 7) << 4))) =
                            (bf16)((acc[mh * 2 + mm][n][i] + bv[n]) * oscale);
                    }
                }
            __builtin_amdgcn_wave_barrier();
            bf16* Cb = (bf16*)Cp + (size_t)(m0 + wm + mh * 32) * N + n0 + wn;
#pragma unroll
            for (int it = 0; it < 4; ++it) {
                int r = it * 8 + (lane >> 3);
                int sl = lane & 7;
                bf16x8 vv = *(const bf16x8*)(myb + r * 128 + ((sl ^ (r & 7)) << 4));
                *(bf16x8*)(Cb + (size_t)r * N + sl * 8) = vv;
            }
            __builtin_amdgcn_wave_barrier();
        }
    }
}

// ---------------------------------------------------------------------------
// kp[b,h,d,r] += sum_{s in chunk} X[b,s,h*64+d] * E[h,s,r]
// E read DIRECTLY as f32 [H,S,R] (fused transpose+convert in registers).
// ---------------------------------------------------------------------------
__global__ __launch_bounds__(256) void kpvp_gemm(const bf16* __restrict__ X,
                                                 const float* __restrict__ E,
                                                 float* __restrict__ out)
{
    __shared__ bf16 Ak[64][40];
    const int b = blockIdx.z, h = blockIdx.y;
    const int s0 = blockIdx.x * 512;
    const int tid = threadIdx.x, wv = tid >> 6, lane = tid & 63;
    const int g = lane >> 4, lr = lane & 15;
    const float* Eh = E + (size_t)h * SS * RR;
    const int rbase = wv * 64 + lr;
    f32x4 acc[4][4] = {};

    for (int kt = 0; kt < 512; kt += 32) {
        const int sb = s0 + kt;
        __syncthreads();
        float ef[4][8];
        const float* Eb = Eh + (size_t)(sb + g * 8) * RR + rbase;
#pragma unroll
        for (int n = 0; n < 4; ++n)
#pragma unroll
            for (int j = 0; j < 8; ++j)
                ef[n][j] = Eb[(size_t)j * RR + n * 16];
        {   // A-stage with transpose: X[b, sb+sl, h*64+dblk+j] -> Ak[dblk+j][sl]
            int sl = tid >> 3, dblk = (tid & 7) * 8;
            bf16x8 v = *(const bf16x8*)(X + ((size_t)b * SS + sb + sl) * DD + h * DK + dblk);
#pragma unroll
            for (int j = 0; j < 8; ++j) Ak[dblk + j][sl] = v[j];
        }
        bf16x8 bb[4];
#pragma unroll
        for (int n = 0; n < 4; ++n)
#pragma unroll
            for (int j = 0; j < 8; ++j)
                bb[n][j] = (bf16)ef[n][j];
        __syncthreads();

        bf16x8 a[4];
#pragma unroll
        for (int m = 0; m < 4; ++m) a[m] = *(const bf16x8*)&Ak[m * 16 + lr][g * 8];
#pragma unroll
        for (int m = 0; m < 4; ++m)
#pragma unroll
            for (int n = 0; n < 4; ++n)
                acc[m][n] = __builtin_amdgcn_mfma_f32_16x16x32_bf16(a[m], bb[n], acc[m][n], 0, 0, 0);
    }

    float* o = out + ((size_t)(b * HH + h)) * DK * RR;
#pragma unroll
    for (int m = 0; m < 4; ++m)
#pragma unroll
        for (int n = 0; n < 4; ++n) {
            int r = wv * 64 + n * 16 + lr;
#pragma unroll
            for (int i = 0; i < 4; ++i)
                atomicAdd(o + (size_t)(m * 16 + 4 * g + i) * RR + r, acc[m][n][i]);
        }
}

// ---------------------------------------------------------------------------
// Fused attention (round-8 structure, frozen at 57us).
// ---------------------------------------------------------------------------
__global__ __launch_bounds__(512) void attn_fused(const bf16* __restrict__ qb,
                                                  const bf16* __restrict__ kpt,
                                                  const bf16* __restrict__ vpb,
                                                  bf16* __restrict__ ctx)
{
    __shared__ bf16 KPs[256][72];
    __shared__ bf16 VPs[64][264];
    __shared__ bf16 Ps[8][16][264];
    const int b = blockIdx.z, h = blockIdx.y, qt = blockIdx.x;
    const int tid = threadIdx.x, wv = tid >> 6, lane = tid & 63;
    const int g = lane >> 4, lr = lane & 15;
    const bf16* kph = kpt + ((size_t)(b * HH + h)) * RR * DK;
    const bf16* vph = vpb + ((size_t)(b * HH + h)) * DK * RR;

#pragma unroll
    for (int p = 0; p < 4; ++p) {
        int f = p * 512 + tid;
        *(bf16x8*)&KPs[f >> 3][(f & 7) * 8] = *(const bf16x8*)(kph + (size_t)f * 8);
        *(bf16x8*)&VPs[f >> 5][(f & 31) * 8] = *(const bf16x8*)(vph + (size_t)f * 8);
    }

    const bf16* qbase = qb + (size_t)b * SS * DD + h * DK;
    int row0 = qt * 1024 + wv * 16;
    bf16x8 aq0 = *(const bf16x8*)(qbase + (size_t)(row0 + lr) * DD + g * 8);
    bf16x8 aq1 = *(const bf16x8*)(qbase + (size_t)(row0 + lr) * DD + 32 + g * 8);
    __syncthreads();

    for (int it = 0; it < 8; ++it) {
        f32x4 acc[16] = {};
        __builtin_amdgcn_s_setprio(1);
#pragma unroll
        for (int nf = 0; nf < 16; ++nf) {
            bf16x8 b0 = *(const bf16x8*)&KPs[nf * 16 + lr][g * 8];
            bf16x8 b1 = *(const bf16x8*)&KPs[nf * 16 + lr][32 + g * 8];
            acc[nf] = __builtin_amdgcn_mfma_f32_16x16x32_bf16(aq0, b0, acc[nf], 0, 0, 0);
            acc[nf] = __builtin_amdgcn_mfma_f32_16x16x32_bf16(aq1, b1, acc[nf], 0, 0, 0);
        }
        __builtin_amdgcn_s_setprio(0);

        bf16x8 aqn0 = aq0, aqn1 = aq1;
        if (it < 7) {
            const bf16* qr = qbase + (size_t)(row0 + 128 + lr) * DD;
            aqn0 = *(const bf16x8*)(qr + g * 8);
            aqn1 = *(const bf16x8*)(qr + 32 + g * 8);
        }

        float rs[4];
#pragma unroll
        for (int i = 0; i < 4; ++i) {
            float s = 0.f;
#pragma unroll
            for (int nf = 0; nf < 16; ++nf) {
                float pv = exp2f(acc[nf][i]);
                acc[nf][i] = pv;
                s += pv;
            }
#pragma unroll
            for (int msk = 1; msk < 16; msk <<= 1) s += __shfl_xor(s, msk, 64);
            rs[i] = 1.f / s;
        }

#pragma unroll
        for (int nf = 0; nf < 16; ++nf)
#pragma unroll
            for (int i = 0; i < 4; ++i)
                Ps[wv][4 * g + i][nf * 16 + lr] = (bf16)acc[nf][i];
        __builtin_amdgcn_wave_barrier();

        f32x4 o[4] = {};
        __builtin_amdgcn_s_setprio(1);
#pragma unroll
        for (int ks = 0; ks < 8; ++ks) {
            bf16x8 pa = *(const bf16x8*)&Ps[wv][lr][ks * 32 + g * 8];
#pragma unroll
            for (int n = 0; n < 4; ++n) {
                bf16x8 vb = *(const bf16x8*)&VPs[n * 16 + lr][ks * 32 + g * 8];
                o[n] = __builtin_amdgcn_mfma_f32_16x16x32_bf16(pa, vb, o[n], 0, 0, 0);
            }
        }
        __builtin_amdgcn_s_setprio(0);
        __builtin_amdgcn_wave_barrier();

#pragma unroll
        for (int n = 0; n < 4; ++n)
#pragma unroll
            for (int i = 0; i < 4; ++i)
                Ps[wv][4 * g + i][n * 16 + lr] = (bf16)(o[n][i] * rs[i]);
        __builtin_amdgcn_wave_barrier();
        bf16* crow = ctx + (size_t)(b * SS + row0) * DD + h * DK;
#pragma unroll
        for (int p = 0; p < 2; ++p) {
            int r = p * 8 + (lane >> 3), c = (lane & 7) * 8;
            bf16x8 ov = *(const bf16x8*)&Ps[wv][r][c];
            *(bf16x8*)(crow + (size_t)r * DD + c) = ov;
        }
        __builtin_amdgcn_wave_barrier();

        aq0 = aqn0; aq1 = aqn1;
        row0 += 128;
    }
}

// ---------------------------------------------------------------------------
extern "C" void kernel_launch(void* const* d_in, const int* in_sizes, int n_in,
                              void* d_out, int out_size, void* d_ws, size_t ws_size,
                              hipStream_t stream)
{
    const float* query = (const float*)d_in[0];
    const float* key   = (const float*)d_in[1];
    const float* value = (const float*)d_in[2];
    const float* Wq = (const float*)d_in[3];  const float* bq = (const float*)d_in[4];
    const float* Wk = (const float*)d_in[5];  const float* bk = (const float*)d_in[6];
    const float* Wv = (const float*)d_in[7];  const float* bv = (const float*)d_in[8];
    const float* Wo = (const float*)d_in[9];  const float* bo = (const float*)d_in[10];
    const float* E  = (const float*)d_in[11];
    const float* F  = (const float*)d_in[12];

    char* w = (char*)d_ws;
    size_t off = 0;
    auto alloc = [&](size_t bytes) -> char* {
        char* p = w + off;
        off += (bytes + 255) & ~(size_t)255;
        return p;
    };

    const size_t DW   = (size_t)DD * DD;           // 1M
    const size_t BSD  = (size_t)BB * SS * DD;      // 16.78M
    const size_t BHDR = (size_t)BB * HH * DK * RR; // 4.19M

    bf16* wqb = (bf16*)alloc(DW * 2);
    bf16* wkb = (bf16*)alloc(DW * 2);
    bf16* wvb = (bf16*)alloc(DW * 2);
    bf16* wob = (bf16*)alloc(DW * 2);
    bf16* qin = (bf16*)alloc(BSD * 2);             // bf16 inputs; later reused:
    bf16* kin = (bf16*)alloc(BSD * 2);             //   qin -> kpf/vpf, kin -> kpt/vp,
    bf16* vin = (bf16*)alloc(BSD * 2);             //   vin -> ctx
    bf16* qbuf = (bf16*)alloc(BSD * 2);
    bf16* kbuf = (bf16*)alloc(BSD * 2);
    bf16* vbuf = (bf16*)alloc(BSD * 2);
    if (off > ws_size) return;

    // aliased scratch (stream-ordered reuse; regions dead by first write)
    float* kpf  = (float*)qin;                     // BHDR f32
    float* vpf  = kpf + BHDR;                      // BHDR f32
    bf16*  kpt  = (bf16*)kin;                      // BHDR bf16 [B,H,R,DK]
    bf16*  vpbb = kpt + BHDR;                      // BHDR bf16 [B,H,DK,R]
    bf16*  ctx  = (bf16*)vin;                      // BSD bf16

    // 1. converts: weights + activations
    cvt_f32_bf16<<<(int)(DW / 2048), 256, 0, stream>>>(Wq, wqb, (int)DW);
    cvt_f32_bf16<<<(int)(DW / 2048), 256, 0, stream>>>(Wk, wkb, (int)DW);
    cvt_f32_bf16<<<(int)(DW / 2048), 256, 0, stream>>>(Wv, wvb, (int)DW);
    cvt_f32_bf16<<<(int)(DW / 2048), 256, 0, stream>>>(Wo, wob, (int)DW);
    cvt_f32_bf16<<<(int)(BSD / 2048), 256, 0, stream>>>(query, qin, (int)BSD);
    cvt_f32_bf16<<<(int)(BSD / 2048), 256, 0, stream>>>(key,   kin, (int)BSD);
    cvt_f32_bf16<<<(int)(BSD / 2048), 256, 0, stream>>>(value, vin, (int)BSD);

    // 2. QKV projections (pipelined gemm; q pre-scaled for exp2 softmax)
    const int nwg = ((BB * SS) / 256) * (DD / 128);   // 512, % 8 == 0
    gemm_bt<false><<<nwg, 512, 0, stream>>>(qin, wqb, bq, qbuf, BB * SS, DD, DD, QSCALE);
    gemm_bt<false><<<nwg, 512, 0, stream>>>(kin, wkb, bk, kbuf, BB * SS, DD, DD, 1.0f);
    gemm_bt<false><<<nwg, 512, 0, stream>>>(vin, wvb, bv, vbuf, BB * SS, DD, DD, 1.0f);

    // 3. kp/vp = k^T E, v^T F — E/F read directly as f32 (fused transpose+cvt)
    hipMemsetAsync(kpf, 0, BHDR * 4 * 2, stream);
    kpvp_gemm<<<dim3(SS / 512, HH, BB), 256, 0, stream>>>(kbuf, E, kpf);
    kpvp_gemm<<<dim3(SS / 512, HH, BB), 256, 0, stream>>>(vbuf, F, vpf);

    // 4. kp -> kpT bf16 [B,H,R,DK]; vp -> bf16 [B,H,DK,R]  (kin region dead)
    dim3 tb(64, 4);
    transpose_cvt<<<dim3(RR / 64, DK / 64, BB * HH), tb, 0, stream>>>(kpf, kpt, DK, RR);
    cvt_f32_bf16<<<(int)(BHDR / 2048), 256, 0, stream>>>(vpf, vpbb, (int)BHDR);

    // 5. fused softmax attention (vin region dead -> ctx)
    attn_fused<<<dim3(SS / 1024, HH, BB), 512, 0, stream>>>(qbuf, kpt, vpbb, ctx);

    // 6. output projection -> f32 d_out
    gemm_bt<true><<<nwg, 512, 0, stream>>>(ctx, wob, bo, d_out, BB * SS, DD, DD, 1.0f);
}

// Round 15
// 384.419 us; speedup vs baseline: 2.8100x; 1.0788x over previous
//
#include <hip/hip_runtime.h>

// ---------------------------------------------------------------------------
// LinearAttention (Linformer-style) on MI355X, bf16 MFMA pipeline, f32 accum.
// B=4 S=4096 D=1024 H=16 R=256 DK=64
// Round 15: EXACT revert to round-10 state (384.9 us, session best).
//   - gemm_bt: r8 structure — 256x128 tile, BK=32, 8 waves, 48KB LDS,
//     launch_bounds(512,4) -> 2-3 blocks/CU co-resident, counted VMW3,
//     2-way-free swizzle. (r14 frag-prefetch at (512,2) regressed: lost
//     co-residency that was already hiding frag-read latency.)
//   - attn_fused: r8 single-accumulator structure (57 us).
//   - kpvp: direct-f32 E/F read (fused transpose+convert).
//   - separate q/k/v converts (fusion attempts r11-r13 all failed).
// ---------------------------------------------------------------------------

typedef __bf16 bf16;
typedef bf16 bf16x8 __attribute__((ext_vector_type(8)));
typedef bf16 bf16x4 __attribute__((ext_vector_type(4)));
typedef float f32x4 __attribute__((ext_vector_type(4)));

constexpr int BB = 4, SS = 4096, DD = 1024, HH = 16, RR = 256, DK = 64;

// q-projection output pre-scale: logits*log2e/8 so softmax uses exp2 directly
#define QSCALE 0.1803368801111204f

// async global->LDS, 16B per lane. ldsbase must be wave-uniform; HW writes
// lane l's 16B at ldsbase + l*16. gptr is per-lane.
__device__ __forceinline__ void gl2lds16(const void* g, void* l, int lane)
{
#if __has_builtin(__builtin_amdgcn_global_load_lds)
    auto gp = reinterpret_cast<const __attribute__((address_space(1))) void*>(
        reinterpret_cast<uintptr_t>(g));
    auto lp = reinterpret_cast<__attribute__((address_space(3))) void*>(
        reinterpret_cast<uintptr_t>(l));
    __builtin_amdgcn_global_load_lds(gp, lp, 16, 0, 0);
    (void)lane;
#else
    *(bf16x8*)((char*)l + lane * 16) = *(const bf16x8*)g;
#endif
}

#define VMW3  asm volatile("s_waitcnt vmcnt(3)" ::: "memory")
#define VMW0  asm volatile("s_waitcnt vmcnt(0)" ::: "memory")
#define LGKM0 asm volatile("s_waitcnt lgkmcnt(0)" ::: "memory")

// ---------------------------------------------------------------------------
// Elementwise f32 -> bf16 convert, 8 elems/thread
// ---------------------------------------------------------------------------
__global__ void cvt_f32_bf16(const float* __restrict__ in, bf16* __restrict__ out, int n)
{
    int i = (blockIdx.x * 256 + threadIdx.x) * 8;
    if (i < n) {
        float4 v0 = *(const float4*)(in + i);
        float4 v1 = *(const float4*)(in + i + 4);
        bf16x8 h;
        h[0] = (bf16)v0.x; h[1] = (bf16)v0.y; h[2] = (bf16)v0.z; h[3] = (bf16)v0.w;
        h[4] = (bf16)v1.x; h[5] = (bf16)v1.y; h[6] = (bf16)v1.z; h[7] = (bf16)v1.w;
        *(bf16x8*)(out + i) = h;
    }
}

// ---------------------------------------------------------------------------
// Tiled transpose + convert (used for kp f32 [DK,R] -> kpT bf16 [R,DK])
// ---------------------------------------------------------------------------
__global__ void transpose_cvt(const float* __restrict__ in, bf16* __restrict__ out,
                              int rows, int cols)
{
    __shared__ float t[64][65];
    const float* I = in + (size_t)blockIdx.z * rows * cols;
    bf16* O = out + (size_t)blockIdx.z * rows * cols;
    int c0 = blockIdx.x * 64, r0 = blockIdx.y * 64;
    int tx = threadIdx.x, ty = threadIdx.y;
#pragma unroll
    for (int i = ty; i < 64; i += 4)
        t[i][tx] = I[(size_t)(r0 + i) * cols + c0 + tx];
    __syncthreads();
#pragma unroll
    for (int i = ty; i < 64; i += 4)
        O[(size_t)(c0 + i) * rows + r0 + tx] = (bf16)t[tx][i];
}

// ---------------------------------------------------------------------------
// C[M,N] = (A[M,K](bf16) * W[N,K]^T(bf16) + bias[N]) * oscale.   K == 1024.
// Round-8 structure (frozen): 256x128 tile, BK=32, 8 waves (4M x 2N), 48KB LDS
// -> co-resident blocks; counted VMW3; 64B-row swizzle.
// ---------------------------------------------------------------------------
template <bool OUT_F32>
__global__ __launch_bounds__(512, 4) void gemm_bt(const bf16* __restrict__ A,
                                                  const bf16* __restrict__ W,
                                                  const float* __restrict__ bias,
                                                  void* __restrict__ Cp,
                                                  int M, int N, int K, float oscale)
{
    __shared__ bf16 As[2][256][32];
    __shared__ bf16 Bs[2][128][32];
    const int tid = threadIdx.x, wv = tid >> 6, lane = tid & 63;
    const int g = lane >> 4, lr = lane & 15;

    const int nwg = gridDim.x;
    const int cpx = nwg >> 3;                      // nwg % 8 == 0 (bijective)
    const int bid = blockIdx.x;
    const int swz = (bid & 7) * cpx + (bid >> 3);
    const int gx = N >> 7;
    const int mt = swz / gx, nt = swz % gx;
    const int m0 = mt * 256, n0 = nt * 128;
    const int wm = (wv >> 1) * 64, wn = (wv & 1) * 64;

    const int srow = lane >> 2;
    const int scol = ((lane & 3) ^ ((lane >> 4) & 3)) * 8;

    f32x4 acc[4][4] = {};

    auto stageA = [&](int buf, int tk) {
#pragma unroll
        for (int s2 = 0; s2 < 2; ++s2) {
            int c = wv * 2 + s2;
            gl2lds16(A + (size_t)(m0 + c * 16 + srow) * 1024 + tk * 32 + scol,
                     &As[buf][c * 16][0], lane);
        }
    };
    auto stageB = [&](int buf, int tk) {
        gl2lds16(W + (size_t)(n0 + wv * 16 + srow) * 1024 + tk * 32 + scol,
                 &Bs[buf][wv * 16][0], lane);
    };

#define PHK(PB, STAGE_STMT, VM_STMT)                                             \
    {                                                                            \
        const int so = (g ^ (lr >> 2)) << 4;                                     \
        bf16x8 aF[4], bF[4];                                                     \
        _Pragma("unroll") for (int mm = 0; mm < 4; ++mm)                         \
            aF[mm] = *(const bf16x8*)((const char*)&As[PB][wm + mm * 16 + lr][0] + so); \
        _Pragma("unroll") for (int nn = 0; nn < 4; ++nn)                         \
            bF[nn] = *(const bf16x8*)((const char*)&Bs[PB][wn + nn * 16 + lr][0] + so); \
        LGKM0;                                                                   \
        __builtin_amdgcn_s_barrier();              /* all waves' reads done */   \
        STAGE_STMT;                                /* overwrite buffer PB */     \
        VM_STMT;                                   /* drain tile t+1 */          \
        __builtin_amdgcn_s_barrier();              /* next buffer visible */     \
        __builtin_amdgcn_sched_barrier(0);                                       \
        __builtin_amdgcn_s_setprio(1);                                           \
        _Pragma("unroll") for (int mm = 0; mm < 4; ++mm) {                       \
            _Pragma("unroll") for (int nn = 0; nn < 4; ++nn) {                   \
                acc[mm][nn] = __builtin_amdgcn_mfma_f32_16x16x32_bf16(           \
                    aF[mm], bF[nn], acc[mm][nn], 0, 0, 0); } }                   \
        __builtin_amdgcn_s_setprio(0);                                           \
    }

    stageA(0, 0); stageB(0, 0);
    stageA(1, 1); stageB(1, 1);
    VMW3;
    __builtin_amdgcn_s_barrier();

#pragma unroll 1
    for (int t = 0; t < 30; ++t) {
        const int pb = t & 1;
        PHK(pb, { stageA(pb, t + 2); stageB(pb, t + 2); }, VMW3);
    }
    PHK(0, (void)0, VMW0);
    PHK(1, (void)0, (void)0);
#undef PHK

    float bv[4];
#pragma unroll
    for (int n = 0; n < 4; ++n) bv[n] = bias[n0 + wn + n * 16 + lr];

    if constexpr (OUT_F32) {
#pragma unroll
        for (int n = 0; n < 4; ++n) {
            int col = n0 + wn + n * 16 + lr;
#pragma unroll
            for (int m = 0; m < 4; ++m) {
                int row = m0 + wm + m * 16 + 4 * g;
#pragma unroll
                for (int i = 0; i < 4; ++i)
                    ((float*)Cp)[(size_t)(row + i) * N + col] = (acc[m][n][i] + bv[n]) * oscale;
            }
        }
    } else {
        char* myb = (char*)&As[0][0][0] + wv * 4096;
#pragma unroll
        for (int mh = 0; mh < 2; ++mh) {
#pragma unroll
            for (int mm = 0; mm < 2; ++mm)
#pragma unroll
                for (int n = 0; n < 4; ++n) {
                    int colb = (n * 16 + lr) * 2;
#pragma unroll
                    for (int i = 0; i < 4; ++i) {
                        int row = mm * 16 + 4 * g + i;
                        *(bf16*)(myb + row * 128 + (colb ^ ((row & 7) << 4))) =
                            (bf16)((acc[mh * 2 + mm][n][i] + bv[n]) * oscale);
                    }
                }
            __builtin_amdgcn_wave_barrier();
            bf16* Cb = (bf16*)Cp + (size_t)(m0 + wm + mh * 32) * N + n0 + wn;
#pragma unroll
            for (int it = 0; it < 4; ++it) {
                int r = it * 8 + (lane >> 3);
                int sl = lane & 7;
                bf16x8 vv = *(const bf16x8*)(myb + r * 128 + ((sl ^ (r & 7)) << 4));
                *(bf16x8*)(Cb + (size_t)r * N + sl * 8) = vv;
            }
            __builtin_amdgcn_wave_barrier();
        }
    }
}

// ---------------------------------------------------------------------------
// kp[b,h,d,r] += sum_{s in chunk} X[b,s,h*64+d] * E[h,s,r]
// E read DIRECTLY as f32 [H,S,R] (fused transpose+convert in registers).
// ---------------------------------------------------------------------------
__global__ __launch_bounds__(256) void kpvp_gemm(const bf16* __restrict__ X,
                                                 const float* __restrict__ E,
                                                 float* __restrict__ out)
{
    __shared__ bf16 Ak[64][40];
    const int b = blockIdx.z, h = blockIdx.y;
    const int s0 = blockIdx.x * 512;
    const int tid = threadIdx.x, wv = tid >> 6, lane = tid & 63;
    const int g = lane >> 4, lr = lane & 15;
    const float* Eh = E + (size_t)h * SS * RR;
    const int rbase = wv * 64 + lr;
    f32x4 acc[4][4] = {};

    for (int kt = 0; kt < 512; kt += 32) {
        const int sb = s0 + kt;
        __syncthreads();
        float ef[4][8];
        const float* Eb = Eh + (size_t)(sb + g * 8) * RR + rbase;
#pragma unroll
        for (int n = 0; n < 4; ++n)
#pragma unroll
            for (int j = 0; j < 8; ++j)
                ef[n][j] = Eb[(size_t)j * RR + n * 16];
        {   // A-stage with transpose: X[b, sb+sl, h*64+dblk+j] -> Ak[dblk+j][sl]
            int sl = tid >> 3, dblk = (tid & 7) * 8;
            bf16x8 v = *(const bf16x8*)(X + ((size_t)b * SS + sb + sl) * DD + h * DK + dblk);
#pragma unroll
            for (int j = 0; j < 8; ++j) Ak[dblk + j][sl] = v[j];
        }
        bf16x8 bb[4];
#pragma unroll
        for (int n = 0; n < 4; ++n)
#pragma unroll
            for (int j = 0; j < 8; ++j)
                bb[n][j] = (bf16)ef[n][j];
        __syncthreads();

        bf16x8 a[4];
#pragma unroll
        for (int m = 0; m < 4; ++m) a[m] = *(const bf16x8*)&Ak[m * 16 + lr][g * 8];
#pragma unroll
        for (int m = 0; m < 4; ++m)
#pragma unroll
            for (int n = 0; n < 4; ++n)
                acc[m][n] = __builtin_amdgcn_mfma_f32_16x16x32_bf16(a[m], bb[n], acc[m][n], 0, 0, 0);
    }

    float* o = out + ((size_t)(b * HH + h)) * DK * RR;
#pragma unroll
    for (int m = 0; m < 4; ++m)
#pragma unroll
        for (int n = 0; n < 4; ++n) {
            int r = wv * 64 + n * 16 + lr;
#pragma unroll
            for (int i = 0; i < 4; ++i)
                atomicAdd(o + (size_t)(m * 16 + 4 * g + i) * RR + r, acc[m][n][i]);
        }
}

// ---------------------------------------------------------------------------
// Fused attention (round-8 structure, measured 57us): 256 blocks x 8 waves,
// single accumulator, KP/VP staged once, barrier-free inner loop, exp2
// softmax, deferred norm, LDS-bounced coalesced ctx stores.
// ---------------------------------------------------------------------------
__global__ __launch_bounds__(512) void attn_fused(const bf16* __restrict__ qb,
                                                  const bf16* __restrict__ kpt,
                                                  const bf16* __restrict__ vpb,
                                                  bf16* __restrict__ ctx)
{
    __shared__ bf16 KPs[256][72];      // kpT tile [r][d]
    __shared__ bf16 VPs[64][264];      // vp tile [d][r]
    __shared__ bf16 Ps[8][16][264];    // per-wave P / out-bounce tile
    const int b = blockIdx.z, h = blockIdx.y, qt = blockIdx.x;
    const int tid = threadIdx.x, wv = tid >> 6, lane = tid & 63;
    const int g = lane >> 4, lr = lane & 15;
    const bf16* kph = kpt + ((size_t)(b * HH + h)) * RR * DK;
    const bf16* vph = vpb + ((size_t)(b * HH + h)) * DK * RR;

#pragma unroll
    for (int p = 0; p < 4; ++p) {
        int f = p * 512 + tid;
        *(bf16x8*)&KPs[f >> 3][(f & 7) * 8] = *(const bf16x8*)(kph + (size_t)f * 8);
        *(bf16x8*)&VPs[f >> 5][(f & 31) * 8] = *(const bf16x8*)(vph + (size_t)f * 8);
    }

    const bf16* qbase = qb + (size_t)b * SS * DD + h * DK;
    int row0 = qt * 1024 + wv * 16;
    bf16x8 aq0 = *(const bf16x8*)(qbase + (size_t)(row0 + lr) * DD + g * 8);
    bf16x8 aq1 = *(const bf16x8*)(qbase + (size_t)(row0 + lr) * DD + 32 + g * 8);
    __syncthreads();

    for (int it = 0; it < 8; ++it) {
        f32x4 acc[16] = {};
        __builtin_amdgcn_s_setprio(1);
#pragma unroll
        for (int nf = 0; nf < 16; ++nf) {
            bf16x8 b0 = *(const bf16x8*)&KPs[nf * 16 + lr][g * 8];
            bf16x8 b1 = *(const bf16x8*)&KPs[nf * 16 + lr][32 + g * 8];
            acc[nf] = __builtin_amdgcn_mfma_f32_16x16x32_bf16(aq0, b0, acc[nf], 0, 0, 0);
            acc[nf] = __builtin_amdgcn_mfma_f32_16x16x32_bf16(aq1, b1, acc[nf], 0, 0, 0);
        }
        __builtin_amdgcn_s_setprio(0);

        bf16x8 aqn0 = aq0, aqn1 = aq1;
        if (it < 7) {
            const bf16* qr = qbase + (size_t)(row0 + 128 + lr) * DD;
            aqn0 = *(const bf16x8*)(qr + g * 8);
            aqn1 = *(const bf16x8*)(qr + 32 + g * 8);
        }

        float rs[4];
#pragma unroll
        for (int i = 0; i < 4; ++i) {
            float s = 0.f;
#pragma unroll
            for (int nf = 0; nf < 16; ++nf) {
                float pv = exp2f(acc[nf][i]);
                acc[nf][i] = pv;
                s += pv;
            }
#pragma unroll
            for (int msk = 1; msk < 16; msk <<= 1) s += __shfl_xor(s, msk, 64);
            rs[i] = 1.f / s;
        }

#pragma unroll
        for (int nf = 0; nf < 16; ++nf)
#pragma unroll
            for (int i = 0; i < 4; ++i)
                Ps[wv][4 * g + i][nf * 16 + lr] = (bf16)acc[nf][i];
        __builtin_amdgcn_wave_barrier();

        f32x4 o[4] = {};
        __builtin_amdgcn_s_setprio(1);
#pragma unroll
        for (int ks = 0; ks < 8; ++ks) {
            bf16x8 pa = *(const bf16x8*)&Ps[wv][lr][ks * 32 + g * 8];
#pragma unroll
            for (int n = 0; n < 4; ++n) {
                bf16x8 vb = *(const bf16x8*)&VPs[n * 16 + lr][ks * 32 + g * 8];
                o[n] = __builtin_amdgcn_mfma_f32_16x16x32_bf16(pa, vb, o[n], 0, 0, 0);
            }
        }
        __builtin_amdgcn_s_setprio(0);
        __builtin_amdgcn_wave_barrier();

#pragma unroll
        for (int n = 0; n < 4; ++n)
#pragma unroll
            for (int i = 0; i < 4; ++i)
                Ps[wv][4 * g + i][n * 16 + lr] = (bf16)(o[n][i] * rs[i]);
        __builtin_amdgcn_wave_barrier();
        bf16* crow = ctx + (size_t)(b * SS + row0) * DD + h * DK;
#pragma unroll
        for (int p = 0; p < 2; ++p) {
            int r = p * 8 + (lane >> 3), c = (lane & 7) * 8;
            bf16x8 ov = *(const bf16x8*)&Ps[wv][r][c];
            *(bf16x8*)(crow + (size_t)r * DD + c) = ov;
        }
        __builtin_amdgcn_wave_barrier();

        aq0 = aqn0; aq1 = aqn1;
        row0 += 128;
    }
}

// ---------------------------------------------------------------------------
extern "C" void kernel_launch(void* const* d_in, const int* in_sizes, int n_in,
                              void* d_out, int out_size, void* d_ws, size_t ws_size,
                              hipStream_t stream)
{
    const float* query = (const float*)d_in[0];
    const float* key   = (const float*)d_in[1];
    const float* value = (const float*)d_in[2];
    const float* Wq = (const float*)d_in[3];  const float* bq = (const float*)d_in[4];
    const float* Wk = (const float*)d_in[5];  const float* bk = (const float*)d_in[6];
    const float* Wv = (const float*)d_in[7];  const float* bv = (const float*)d_in[8];
    const float* Wo = (const float*)d_in[9];  const float* bo = (const float*)d_in[10];
    const float* E  = (const float*)d_in[11];
    const float* F  = (const float*)d_in[12];

    char* w = (char*)d_ws;
    size_t off = 0;
    auto alloc = [&](size_t bytes) -> char* {
        char* p = w + off;
        off += (bytes + 255) & ~(size_t)255;
        return p;
    };

    const size_t DW   = (size_t)DD * DD;           // 1M
    const size_t BSD  = (size_t)BB * SS * DD;      // 16.78M
    const size_t BHDR = (size_t)BB * HH * DK * RR; // 4.19M

    bf16* wqb = (bf16*)alloc(DW * 2);
    bf16* wkb = (bf16*)alloc(DW * 2);
    bf16* wvb = (bf16*)alloc(DW * 2);
    bf16* wob = (bf16*)alloc(DW * 2);
    bf16* qin = (bf16*)alloc(BSD * 2);             // bf16 inputs; later reused:
    bf16* kin = (bf16*)alloc(BSD * 2);             //   qin -> kpf/vpf, kin -> kpt/vp,
    bf16* vin = (bf16*)alloc(BSD * 2);             //   vin -> ctx
    bf16* qbuf = (bf16*)alloc(BSD * 2);
    bf16* kbuf = (bf16*)alloc(BSD * 2);
    bf16* vbuf = (bf16*)alloc(BSD * 2);
    if (off > ws_size) return;

    // aliased scratch (stream-ordered reuse; regions dead by first write)
    float* kpf  = (float*)qin;                     // BHDR f32
    float* vpf  = kpf + BHDR;                      // BHDR f32
    bf16*  kpt  = (bf16*)kin;                      // BHDR bf16 [B,H,R,DK]
    bf16*  vpbb = kpt + BHDR;                      // BHDR bf16 [B,H,DK,R]
    bf16*  ctx  = (bf16*)vin;                      // BSD bf16

    // 1. converts: weights + activations
    cvt_f32_bf16<<<(int)(DW / 2048), 256, 0, stream>>>(Wq, wqb, (int)DW);
    cvt_f32_bf16<<<(int)(DW / 2048), 256, 0, stream>>>(Wk, wkb, (int)DW);
    cvt_f32_bf16<<<(int)(DW / 2048), 256, 0, stream>>>(Wv, wvb, (int)DW);
    cvt_f32_bf16<<<(int)(DW / 2048), 256, 0, stream>>>(Wo, wob, (int)DW);
    cvt_f32_bf16<<<(int)(BSD / 2048), 256, 0, stream>>>(query, qin, (int)BSD);
    cvt_f32_bf16<<<(int)(BSD / 2048), 256, 0, stream>>>(key,   kin, (int)BSD);
    cvt_f32_bf16<<<(int)(BSD / 2048), 256, 0, stream>>>(value, vin, (int)BSD);

    // 2. QKV projections (256x128 co-resident GEMM; q pre-scaled for exp2)
    const int nwg = ((BB * SS) / 256) * (DD / 128);   // 512, % 8 == 0
    gemm_bt<false><<<nwg, 512, 0, stream>>>(qin, wqb, bq, qbuf, BB * SS, DD, DD, QSCALE);
    gemm_bt<false><<<nwg, 512, 0, stream>>>(kin, wkb, bk, kbuf, BB * SS, DD, DD, 1.0f);
    gemm_bt<false><<<nwg, 512, 0, stream>>>(vin, wvb, bv, vbuf, BB * SS, DD, DD, 1.0f);

    // 3. kp/vp = k^T E, v^T F — E/F read directly as f32 (fused transpose+cvt)
    hipMemsetAsync(kpf, 0, BHDR * 4 * 2, stream);
    kpvp_gemm<<<dim3(SS / 512, HH, BB), 256, 0, stream>>>(kbuf, E, kpf);
    kpvp_gemm<<<dim3(SS / 512, HH, BB), 256, 0, stream>>>(vbuf, F, vpf);

    // 4. kp -> kpT bf16 [B,H,R,DK]; vp -> bf16 [B,H,DK,R]  (kin region dead)
    dim3 tb(64, 4);
    transpose_cvt<<<dim3(RR / 64, DK / 64, BB * HH), tb, 0, stream>>>(kpf, kpt, DK, RR);
    cvt_f32_bf16<<<(int)(BHDR / 2048), 256, 0, stream>>>(vpf, vpbb, (int)BHDR);

    // 5. fused softmax attention (vin region dead -> ctx)
    attn_fused<<<dim3(SS / 1024, HH, BB), 512, 0, stream>>>(qbuf, kpt, vpbb, ctx);

    // 6. output projection -> f32 d_out
    gemm_bt<true><<<nwg, 512, 0, stream>>>(ctx, wob, bo, d_out, BB * SS, DD, DD, 1.0f);
}